// Round 1
// baseline (5711.749 us; speedup 1.0000x reference)
//
#include <hip/hip_runtime.h>

#define D 128
#define EDGES 25000

// ---------------- GEMM: h = x @ theta + bias ----------------
// theta (128x128 = 64KB) staged in LDS. 8 rows/block, 32 threads/row,
// each thread computes 4 output columns.
__global__ __launch_bounds__(256) void gemm_kernel(
    const float* __restrict__ x, const float* __restrict__ theta,
    const float* __restrict__ bias, float* __restrict__ h, int n) {
  __shared__ float th[D * D];
  for (int i = threadIdx.x * 4; i < D * D; i += 256 * 4) {
    *(float4*)&th[i] = *(const float4*)&theta[i];
  }
  __syncthreads();
  int row = blockIdx.x * 8 + (threadIdx.x >> 5);
  if (row >= n) return;
  int c0 = (threadIdx.x & 31) * 4;
  const float* xr = x + (size_t)row * D;
  float ax = 0.f, ay = 0.f, az = 0.f, aw = 0.f;
#pragma unroll 8
  for (int k = 0; k < D; ++k) {
    float xv = xr[k];
    float4 t = *(float4*)&th[k * D + c0];
    ax = fmaf(xv, t.x, ax);
    ay = fmaf(xv, t.y, ay);
    az = fmaf(xv, t.z, az);
    aw = fmaf(xv, t.w, aw);
  }
  float4 b = *(const float4*)&bias[c0];
  float4 r;
  r.x = ax + b.x; r.y = ay + b.y; r.z = az + b.z; r.w = aw + b.w;
  *(float4*)&h[(size_t)row * D + c0] = r;
}

// ---------------- scatter-add: dst[didx[p]] += src[sidx[p]] ----------------
// 32 lanes per pair, float4 per lane. Optional count accumulation.
__global__ __launch_bounds__(256) void scatter_kernel(
    const float* __restrict__ src, const int* __restrict__ sidx,
    const int* __restrict__ didx, float* __restrict__ dst,
    float* __restrict__ cnt, int nnz) {
  int p = blockIdx.x * 8 + (threadIdx.x >> 5);
  if (p >= nnz) return;
  int lane = threadIdx.x & 31;
  int s = sidx[p], d = didx[p];
  float4 v = *(const float4*)&src[(size_t)s * D + lane * 4];
  float* dp = &dst[(size_t)d * D + lane * 4];
  unsafeAtomicAdd(dp + 0, v.x);
  unsafeAtomicAdd(dp + 1, v.y);
  unsafeAtomicAdd(dp + 2, v.z);
  unsafeAtomicAdd(dp + 3, v.w);
  if (cnt != nullptr && lane == 0) unsafeAtomicAdd(&cnt[d], 1.0f);
}

// ---------------- normalize rows by max(cnt,1) ----------------
__global__ __launch_bounds__(256) void norm_kernel(
    float* __restrict__ buf, const float* __restrict__ cnt, int rows) {
  int i = blockIdx.x * 256 + threadIdx.x;  // float4 index
  if (i >= rows * (D / 4)) return;
  int row = i >> 5;
  float s = 1.0f / fmaxf(cnt[row], 1.0f);
  float4 v = *(float4*)&buf[(size_t)i * 4];
  v.x *= s; v.y *= s; v.z *= s; v.w *= s;
  *(float4*)&buf[(size_t)i * 4] = v;
}

// ---------------- normalize e_feat2 + attention sigmoid ----------------
// one 64-lane wave per edge; shuffle-reduce the dot product.
__global__ __launch_bounds__(256) void norm_att_kernel(
    float* __restrict__ ef, const float* __restrict__ cnt,
    const float* __restrict__ att_w, const float* __restrict__ att_b,
    float* __restrict__ w, int e_count) {
  int e = blockIdx.x * 4 + (threadIdx.x >> 6);
  if (e >= e_count) return;
  int lane = threadIdx.x & 63;
  float s = 1.0f / fmaxf(cnt[e], 1.0f);
  float2 v = *(float2*)&ef[(size_t)e * D + lane * 2];
  v.x *= s; v.y *= s;
  *(float2*)&ef[(size_t)e * D + lane * 2] = v;
  float2 aw = *(const float2*)&att_w[lane * 2];
  float part = v.x * aw.x + v.y * aw.y;
#pragma unroll
  for (int off = 32; off > 0; off >>= 1) part += __shfl_xor(part, off);
  if (lane == 0) w[e] = 1.0f / (1.0f + expf(-(part + att_b[0])));
}

// ---------------- weighted scatter: out[v] += w[e]*ef[e]; den[v] += w[e] ----
__global__ __launch_bounds__(256) void scatter_w_kernel(
    const float* __restrict__ ef, const float* __restrict__ w,
    const int* __restrict__ nidx, const int* __restrict__ eidx,
    float* __restrict__ out, float* __restrict__ den, int nnz) {
  int p = blockIdx.x * 8 + (threadIdx.x >> 5);
  if (p >= nnz) return;
  int lane = threadIdx.x & 31;
  int e = eidx[p], v = nidx[p];
  float wp = w[e];
  float4 xv = *(const float4*)&ef[(size_t)e * D + lane * 4];
  float* dp = &out[(size_t)v * D + lane * 4];
  unsafeAtomicAdd(dp + 0, wp * xv.x);
  unsafeAtomicAdd(dp + 1, wp * xv.y);
  unsafeAtomicAdd(dp + 2, wp * xv.z);
  unsafeAtomicAdd(dp + 3, wp * xv.w);
  if (lane == 0) unsafeAtomicAdd(&den[v], wp);
}

// ---------------- finalize: out[v] /= max(den[v], 1e-12) ----------------
__global__ __launch_bounds__(256) void finalize_kernel(
    float* __restrict__ out, const float* __restrict__ den, int rows) {
  int i = blockIdx.x * 256 + threadIdx.x;  // float4 index
  if (i >= rows * (D / 4)) return;
  int row = i >> 5;
  float s = 1.0f / fmaxf(den[row], 1e-12f);
  float4 v = *(float4*)&out[(size_t)i * 4];
  v.x *= s; v.y *= s; v.z *= s; v.w *= s;
  *(float4*)&out[(size_t)i * 4] = v;
}

extern "C" void kernel_launch(void* const* d_in, const int* in_sizes, int n_in,
                              void* d_out, int out_size, void* d_ws, size_t ws_size,
                              hipStream_t stream) {
  const float* x       = (const float*)d_in[0];
  const float* theta   = (const float*)d_in[1];
  const float* bias    = (const float*)d_in[2];
  const float* att_w   = (const float*)d_in[3];
  const float* att_b   = (const float*)d_in[4];
  const int*   node_idx = (const int*)d_in[5];
  const int*   edge_idx = (const int*)d_in[6];
  int n   = in_sizes[0] / D;   // 100000
  int nnz = in_sizes[5];       // 800000
  int E   = EDGES;             // 25000 (fixed problem constant)
  float* out = (float*)d_out;

  // workspace layout (floats)
  float* ws    = (float*)d_ws;
  float* h     = ws;                      // n*D
  float* ef    = h + (size_t)n * D;       // E*D
  float* e_cnt = ef + (size_t)E * D;      // E
  float* n_cnt = e_cnt + E;               // n
  float* den   = n_cnt + n;               // n
  float* w     = den + n;                 // E

  int sblocks  = (nnz + 7) / 8;
  int nblocks4 = (n * (D / 4) + 255) / 256;
  int eblocks4 = (E * (D / 4) + 255) / 256;

  // zero accumulators (e_cnt and n_cnt are contiguous)
  hipMemsetAsync(ef, 0, (size_t)E * D * sizeof(float), stream);
  hipMemsetAsync(e_cnt, 0, ((size_t)E + n) * sizeof(float), stream);

  // 1) h = x@theta + bias
  gemm_kernel<<<(n + 7) / 8, 256, 0, stream>>>(x, theta, bias, h, n);

  // 2) e_feat = segment_mean(h[node_idx], edge_idx, E)
  scatter_kernel<<<sblocks, 256, 0, stream>>>(h, node_idx, edge_idx, ef, e_cnt, nnz);
  norm_kernel<<<eblocks4, 256, 0, stream>>>(ef, e_cnt, E);

  // 3) h2 = segment_mean(e_feat[edge_idx], node_idx, N)   (reuse h buffer)
  hipMemsetAsync(h, 0, (size_t)n * D * sizeof(float), stream);
  scatter_kernel<<<sblocks, 256, 0, stream>>>(ef, edge_idx, node_idx, h, n_cnt, nnz);
  norm_kernel<<<nblocks4, 256, 0, stream>>>(h, n_cnt, n);

  // 4) e_feat2 = segment_mean(h2[node_idx], edge_idx, E)  (reuse ef buffer, e_cnt)
  hipMemsetAsync(ef, 0, (size_t)E * D * sizeof(float), stream);
  scatter_kernel<<<sblocks, 256, 0, stream>>>(h, node_idx, edge_idx, ef, nullptr, nnz);

  // 5) normalize e_feat2 + w = sigmoid(e_feat2 @ att_w + att_b)
  norm_att_kernel<<<(E + 3) / 4, 256, 0, stream>>>(ef, e_cnt, att_w, att_b, w, E);

  // 6) num/den scatter into out, then divide
  hipMemsetAsync(out, 0, (size_t)n * D * sizeof(float), stream);
  hipMemsetAsync(den, 0, (size_t)n * sizeof(float), stream);
  scatter_w_kernel<<<sblocks, 256, 0, stream>>>(ef, w, node_idx, edge_idx, out, den, nnz);
  finalize_kernel<<<nblocks4, 256, 0, stream>>>(out, den, n);
}

// Round 2
// 564.223 us; speedup vs baseline: 10.1232x; 10.1232x over previous
//
#include <hip/hip_runtime.h>

#define D 128
#define EDGES 25000

// ================= GEMM: h = x @ theta + bias =================
__global__ __launch_bounds__(256) void gemm_kernel(
    const float* __restrict__ x, const float* __restrict__ theta,
    const float* __restrict__ bias, float* __restrict__ h, int n) {
  __shared__ float th[D * D];
  for (int i = threadIdx.x * 4; i < D * D; i += 256 * 4) {
    *(float4*)&th[i] = *(const float4*)&theta[i];
  }
  __syncthreads();
  int row = blockIdx.x * 8 + (threadIdx.x >> 5);
  if (row >= n) return;
  int c0 = (threadIdx.x & 31) * 4;
  const float* xr = x + (size_t)row * D;
  float ax = 0.f, ay = 0.f, az = 0.f, aw = 0.f;
#pragma unroll 8
  for (int k = 0; k < D; ++k) {
    float xv = xr[k];
    float4 t = *(float4*)&th[k * D + c0];
    ax = fmaf(xv, t.x, ax);
    ay = fmaf(xv, t.y, ay);
    az = fmaf(xv, t.z, az);
    aw = fmaf(xv, t.w, aw);
  }
  float4 b = *(const float4*)&bias[c0];
  float4 r;
  r.x = ax + b.x; r.y = ay + b.y; r.z = az + b.z; r.w = aw + b.w;
  *(float4*)&h[(size_t)row * D + c0] = r;
}

// ================= CSR build =================
__global__ __launch_bounds__(256) void hist_kernel(
    const int* __restrict__ nidx, const int* __restrict__ eidx,
    int* __restrict__ ncnt, int* __restrict__ ecnt, int nnz) {
  int p = blockIdx.x * 256 + threadIdx.x;
  if (p >= nnz) return;
  atomicAdd(&ecnt[eidx[p]], 1);
  atomicAdd(&ncnt[nidx[p]], 1);
}

// exclusive scan, 1024 elems per block (4/thread), Hillis-Steele in LDS
__global__ __launch_bounds__(256) void scan_block_kernel(
    const int* __restrict__ in, int* __restrict__ out, int* __restrict__ bsum, int n) {
  __shared__ int s[256];
  int t = threadIdx.x;
  int base = blockIdx.x * 1024 + t * 4;
  int c0 = (base + 0 < n) ? in[base + 0] : 0;
  int c1 = (base + 1 < n) ? in[base + 1] : 0;
  int c2 = (base + 2 < n) ? in[base + 2] : 0;
  int c3 = (base + 3 < n) ? in[base + 3] : 0;
  int lsum = c0 + c1 + c2 + c3;
  s[t] = lsum;
  __syncthreads();
  for (int off = 1; off < 256; off <<= 1) {
    int a = (t >= off) ? s[t - off] : 0;
    __syncthreads();
    s[t] += a;
    __syncthreads();
  }
  int excl = s[t] - lsum;
  if (base + 0 < n) out[base + 0] = excl;
  if (base + 1 < n) out[base + 1] = excl + c0;
  if (base + 2 < n) out[base + 2] = excl + c0 + c1;
  if (base + 3 < n) out[base + 3] = excl + c0 + c1 + c2;
  if (t == 255) bsum[blockIdx.x] = s[255];
}

__global__ __launch_bounds__(256) void scan_add_kernel(
    int* __restrict__ out, const int* __restrict__ bsum,
    const int* __restrict__ cnt, int n) {
  int i = blockIdx.x * 256 + threadIdx.x;
  if (i >= n) return;
  int v = out[i] + bsum[i >> 10];
  out[i] = v;
  if (i == n - 1) out[n] = v + cnt[i];
}

__global__ __launch_bounds__(256) void fill_kernel(
    const int* __restrict__ nidx, const int* __restrict__ eidx,
    const int* __restrict__ e_off, const int* __restrict__ n_off,
    int* __restrict__ ecur, int* __restrict__ ncur,
    int* __restrict__ e_nodes, int* __restrict__ n_edges, int nnz) {
  int p = blockIdx.x * 256 + threadIdx.x;
  if (p >= nnz) return;
  int node = nidx[p], edge = eidx[p];
  int pe = e_off[edge] + atomicAdd(&ecur[edge], 1);
  e_nodes[pe] = node;
  int pn = n_off[node] + atomicAdd(&ncur[node], 1);
  n_edges[pn] = edge;
}

// ================= segment-mean gather: one wave per segment =================
__global__ __launch_bounds__(256) void gather_mean_kernel(
    const float* __restrict__ src, const int* __restrict__ off,
    const int* __restrict__ list, float* __restrict__ dst, int nseg) {
  int seg = blockIdx.x * 4 + (threadIdx.x >> 6);
  if (seg >= nseg) return;
  int lane = threadIdx.x & 63;
  int col = lane * 2;
  int s0 = off[seg], s1 = off[seg + 1];
  float ax = 0.f, ay = 0.f;
  for (int base = s0; base < s1; base += 64) {
    int m = base + lane;
    int myidx = (m < s1) ? list[m] : 0;
    int cnt = min(64, s1 - base);
    int j = 0;
    for (; j + 4 <= cnt; j += 4) {
      int r0 = __shfl(myidx, j + 0);
      int r1 = __shfl(myidx, j + 1);
      int r2 = __shfl(myidx, j + 2);
      int r3 = __shfl(myidx, j + 3);
      float2 v0 = *(const float2*)&src[(size_t)r0 * D + col];
      float2 v1 = *(const float2*)&src[(size_t)r1 * D + col];
      float2 v2 = *(const float2*)&src[(size_t)r2 * D + col];
      float2 v3 = *(const float2*)&src[(size_t)r3 * D + col];
      ax += v0.x + v1.x + v2.x + v3.x;
      ay += v0.y + v1.y + v2.y + v3.y;
    }
    for (; j < cnt; ++j) {
      int r = __shfl(myidx, j);
      float2 v = *(const float2*)&src[(size_t)r * D + col];
      ax += v.x; ay += v.y;
    }
  }
  float inv = 1.0f / fmaxf((float)(s1 - s0), 1.0f);
  float2 o; o.x = ax * inv; o.y = ay * inv;
  *(float2*)&dst[(size_t)seg * D + col] = o;
}

// ====== segment-mean gather + attention: ef2 row + w = sigmoid(row.att_w+b) ======
__global__ __launch_bounds__(256) void gather_mean_att_kernel(
    const float* __restrict__ src, const int* __restrict__ off,
    const int* __restrict__ list, float* __restrict__ dst,
    const float* __restrict__ att_w, const float* __restrict__ att_b,
    float* __restrict__ w, int nseg) {
  int seg = blockIdx.x * 4 + (threadIdx.x >> 6);
  if (seg >= nseg) return;
  int lane = threadIdx.x & 63;
  int col = lane * 2;
  int s0 = off[seg], s1 = off[seg + 1];
  float ax = 0.f, ay = 0.f;
  for (int base = s0; base < s1; base += 64) {
    int m = base + lane;
    int myidx = (m < s1) ? list[m] : 0;
    int cnt = min(64, s1 - base);
    int j = 0;
    for (; j + 4 <= cnt; j += 4) {
      int r0 = __shfl(myidx, j + 0);
      int r1 = __shfl(myidx, j + 1);
      int r2 = __shfl(myidx, j + 2);
      int r3 = __shfl(myidx, j + 3);
      float2 v0 = *(const float2*)&src[(size_t)r0 * D + col];
      float2 v1 = *(const float2*)&src[(size_t)r1 * D + col];
      float2 v2 = *(const float2*)&src[(size_t)r2 * D + col];
      float2 v3 = *(const float2*)&src[(size_t)r3 * D + col];
      ax += v0.x + v1.x + v2.x + v3.x;
      ay += v0.y + v1.y + v2.y + v3.y;
    }
    for (; j < cnt; ++j) {
      int r = __shfl(myidx, j);
      float2 v = *(const float2*)&src[(size_t)r * D + col];
      ax += v.x; ay += v.y;
    }
  }
  float inv = 1.0f / fmaxf((float)(s1 - s0), 1.0f);
  ax *= inv; ay *= inv;
  float2 o; o.x = ax; o.y = ay;
  *(float2*)&dst[(size_t)seg * D + col] = o;
  float2 awv = *(const float2*)&att_w[col];
  float part = ax * awv.x + ay * awv.y;
#pragma unroll
  for (int offd = 32; offd > 0; offd >>= 1) part += __shfl_xor(part, offd);
  if (lane == 0) w[seg] = 1.0f / (1.0f + expf(-(part + att_b[0])));
}

// ====== final: out[v] = sum_e w[e]*ef2[e] / max(sum_e w[e], 1e-12) ======
__global__ __launch_bounds__(256) void gather_weighted_kernel(
    const float* __restrict__ ef, const float* __restrict__ w,
    const int* __restrict__ off, const int* __restrict__ list,
    float* __restrict__ out, int nseg) {
  int seg = blockIdx.x * 4 + (threadIdx.x >> 6);
  if (seg >= nseg) return;
  int lane = threadIdx.x & 63;
  int col = lane * 2;
  int s0 = off[seg], s1 = off[seg + 1];
  float ax = 0.f, ay = 0.f, wsum = 0.f;
  for (int base = s0; base < s1; base += 64) {
    int m = base + lane;
    int myidx = (m < s1) ? list[m] : 0;
    float myw = (m < s1) ? w[myidx] : 0.f;
    int cnt = min(64, s1 - base);
    int j = 0;
    for (; j + 2 <= cnt; j += 2) {
      int r0 = __shfl(myidx, j + 0);
      int r1 = __shfl(myidx, j + 1);
      float w0 = __shfl(myw, j + 0);
      float w1 = __shfl(myw, j + 1);
      float2 v0 = *(const float2*)&ef[(size_t)r0 * D + col];
      float2 v1 = *(const float2*)&ef[(size_t)r1 * D + col];
      ax = fmaf(w0, v0.x, ax); ay = fmaf(w0, v0.y, ay);
      ax = fmaf(w1, v1.x, ax); ay = fmaf(w1, v1.y, ay);
      wsum += w0 + w1;
    }
    for (; j < cnt; ++j) {
      int r = __shfl(myidx, j);
      float w0 = __shfl(myw, j);
      float2 v = *(const float2*)&ef[(size_t)r * D + col];
      ax = fmaf(w0, v.x, ax); ay = fmaf(w0, v.y, ay);
      wsum += w0;
    }
  }
  float invd = 1.0f / fmaxf(wsum, 1e-12f);
  float2 o; o.x = ax * invd; o.y = ay * invd;
  *(float2*)&out[(size_t)seg * D + col] = o;
}

extern "C" void kernel_launch(void* const* d_in, const int* in_sizes, int n_in,
                              void* d_out, int out_size, void* d_ws, size_t ws_size,
                              hipStream_t stream) {
  const float* x        = (const float*)d_in[0];
  const float* theta    = (const float*)d_in[1];
  const float* bias     = (const float*)d_in[2];
  const float* att_w    = (const float*)d_in[3];
  const float* att_b    = (const float*)d_in[4];
  const int*   node_idx = (const int*)d_in[5];
  const int*   edge_idx = (const int*)d_in[6];
  int n   = in_sizes[0] / D;   // 100000
  int nnz = in_sizes[5];       // 800000
  int E   = EDGES;             // 25000
  float* out = (float*)d_out;

  // ---- workspace layout ----
  char* p = (char*)d_ws;
  float* h  = (float*)p;            p += (size_t)n * D * sizeof(float);
  float* ef = (float*)p;            p += (size_t)E * D * sizeof(float);
  float* w  = (float*)p;            p += (size_t)E * sizeof(float);
  int* e_off   = (int*)p;           p += (size_t)(E + 1) * sizeof(int);
  int* n_off   = (int*)p;           p += (size_t)(n + 1) * sizeof(int);
  int* e_nodes = (int*)p;           p += (size_t)nnz * sizeof(int);
  int* n_edges = (int*)p;           p += (size_t)nnz * sizeof(int);
  int* ecnt    = (int*)p;           p += (size_t)E * sizeof(int);   // also cursor
  int* ncnt    = (int*)p;           p += (size_t)n * sizeof(int);   // also cursor
  int* bsum    = (int*)p;           p += 1024 * sizeof(int);
  int* dummy   = (int*)p;           p += 64 * sizeof(int);

  int nb_e = (E + 1023) / 1024;    // 25
  int nb_n = (n + 1023) / 1024;    // 98

  // ---- CSR build ----
  hipMemsetAsync(ecnt, 0, ((size_t)E + n) * sizeof(int), stream);
  hist_kernel<<<(nnz + 255) / 256, 256, 0, stream>>>(node_idx, edge_idx, ncnt, ecnt, nnz);

  scan_block_kernel<<<nb_e, 256, 0, stream>>>(ecnt, e_off, bsum, E);
  scan_block_kernel<<<1, 256, 0, stream>>>(bsum, bsum, dummy, nb_e);
  scan_add_kernel<<<(E + 255) / 256, 256, 0, stream>>>(e_off, bsum, ecnt, E);

  scan_block_kernel<<<nb_n, 256, 0, stream>>>(ncnt, n_off, bsum, n);
  scan_block_kernel<<<1, 256, 0, stream>>>(bsum, bsum, dummy, nb_n);
  scan_add_kernel<<<(n + 255) / 256, 256, 0, stream>>>(n_off, bsum, ncnt, n);

  hipMemsetAsync(ecnt, 0, ((size_t)E + n) * sizeof(int), stream);  // cursors
  fill_kernel<<<(nnz + 255) / 256, 256, 0, stream>>>(
      node_idx, edge_idx, e_off, n_off, ecnt, ncnt, e_nodes, n_edges, nnz);

  // ---- 1) h = x@theta + bias ----
  gemm_kernel<<<(n + 7) / 8, 256, 0, stream>>>(x, theta, bias, h, n);

  // ---- 2) e_feat = mean over edge members of h ----
  gather_mean_kernel<<<(E + 3) / 4, 256, 0, stream>>>(h, e_off, e_nodes, ef, E);

  // ---- 3) h2 = mean over node's incident edges of e_feat (reuse h) ----
  gather_mean_kernel<<<(n + 3) / 4, 256, 0, stream>>>(ef, n_off, n_edges, h, n);

  // ---- 4+5) e_feat2 = mean over edge members of h2; w = sigmoid(ef2.att_w+b) ----
  gather_mean_att_kernel<<<(E + 3) / 4, 256, 0, stream>>>(
      h, e_off, e_nodes, ef, att_w, att_b, w, E);

  // ---- 6) out = weighted mean over node's incident edges ----
  gather_weighted_kernel<<<(n + 3) / 4, 256, 0, stream>>>(ef, w, n_off, n_edges, out, n);
}

// Round 3
// 493.290 us; speedup vs baseline: 11.5789x; 1.1438x over previous
//
#include <hip/hip_runtime.h>

#define D 128
#define EDGES 25000

// ================= CSR build =================
__global__ __launch_bounds__(256) void hist_kernel(
    const int* __restrict__ nidx, const int* __restrict__ eidx,
    int* __restrict__ ncnt, int* __restrict__ ecnt, int nnz) {
  int p = blockIdx.x * 256 + threadIdx.x;
  if (p >= nnz) return;
  atomicAdd(&ecnt[eidx[p]], 1);
  atomicAdd(&ncnt[nidx[p]], 1);
}

// exclusive scan, 1024 elems per block (4/thread), Hillis-Steele in LDS
__global__ __launch_bounds__(256) void scan_block_kernel(
    const int* __restrict__ in, int* __restrict__ out, int* __restrict__ bsum, int n) {
  __shared__ int s[256];
  int t = threadIdx.x;
  int base = blockIdx.x * 1024 + t * 4;
  int c0 = (base + 0 < n) ? in[base + 0] : 0;
  int c1 = (base + 1 < n) ? in[base + 1] : 0;
  int c2 = (base + 2 < n) ? in[base + 2] : 0;
  int c3 = (base + 3 < n) ? in[base + 3] : 0;
  int lsum = c0 + c1 + c2 + c3;
  s[t] = lsum;
  __syncthreads();
  for (int off = 1; off < 256; off <<= 1) {
    int a = (t >= off) ? s[t - off] : 0;
    __syncthreads();
    s[t] += a;
    __syncthreads();
  }
  int excl = s[t] - lsum;
  if (base + 0 < n) out[base + 0] = excl;
  if (base + 1 < n) out[base + 1] = excl + c0;
  if (base + 2 < n) out[base + 2] = excl + c0 + c1;
  if (base + 3 < n) out[base + 3] = excl + c0 + c1 + c2;
  if (t == 255) bsum[blockIdx.x] = s[255];
}

__global__ __launch_bounds__(256) void scan_add_kernel(
    int* __restrict__ out, const int* __restrict__ bsum,
    const int* __restrict__ cnt, int n) {
  int i = blockIdx.x * 256 + threadIdx.x;
  if (i >= n) return;
  int v = out[i] + bsum[i >> 10];
  out[i] = v;
  if (i == n - 1) out[n] = v + cnt[i];
}

__global__ __launch_bounds__(256) void fill_kernel(
    const int* __restrict__ nidx, const int* __restrict__ eidx,
    const int* __restrict__ e_off, const int* __restrict__ n_off,
    int* __restrict__ ecur, int* __restrict__ ncur,
    int* __restrict__ e_nodes, int* __restrict__ n_edges, int nnz) {
  int p = blockIdx.x * 256 + threadIdx.x;
  if (p >= nnz) return;
  int node = nidx[p], edge = eidx[p];
  int pe = e_off[edge] + atomicAdd(&ecur[edge], 1);
  e_nodes[pe] = node;
  int pn = n_off[node] + atomicAdd(&ncur[node], 1);
  n_edges[pn] = edge;
}

// ================= segment-mean gather: one wave per segment =================
__global__ __launch_bounds__(256) void gather_mean_kernel(
    const float* __restrict__ src, const int* __restrict__ off,
    const int* __restrict__ list, float* __restrict__ dst, int nseg) {
  int seg = blockIdx.x * 4 + (threadIdx.x >> 6);
  if (seg >= nseg) return;
  int lane = threadIdx.x & 63;
  int col = lane * 2;
  int s0 = off[seg], s1 = off[seg + 1];
  float ax = 0.f, ay = 0.f;
  for (int base = s0; base < s1; base += 64) {
    int m = base + lane;
    int myidx = (m < s1) ? list[m] : 0;
    int cnt = min(64, s1 - base);
    int j = 0;
    for (; j + 4 <= cnt; j += 4) {
      int r0 = __shfl(myidx, j + 0);
      int r1 = __shfl(myidx, j + 1);
      int r2 = __shfl(myidx, j + 2);
      int r3 = __shfl(myidx, j + 3);
      float2 v0 = *(const float2*)&src[(size_t)r0 * D + col];
      float2 v1 = *(const float2*)&src[(size_t)r1 * D + col];
      float2 v2 = *(const float2*)&src[(size_t)r2 * D + col];
      float2 v3 = *(const float2*)&src[(size_t)r3 * D + col];
      ax += v0.x + v1.x + v2.x + v3.x;
      ay += v0.y + v1.y + v2.y + v3.y;
    }
    for (; j < cnt; ++j) {
      int r = __shfl(myidx, j);
      float2 v = *(const float2*)&src[(size_t)r * D + col];
      ax += v.x; ay += v.y;
    }
  }
  float inv = 1.0f / fmaxf((float)(s1 - s0), 1.0f);
  float2 o; o.x = ax * inv; o.y = ay * inv;
  *(float2*)&dst[(size_t)seg * D + col] = o;
}

// ====== fused small GEMM + attention: ef2 = xm3@theta + bias, w = sigmoid(ef2.att_w+att_b)
// one wave per row; theta staged in LDS; x-row broadcast via shfl.
__global__ __launch_bounds__(256) void gemm_att_kernel(
    const float* __restrict__ xm3, const float* __restrict__ theta,
    const float* __restrict__ bias, const float* __restrict__ att_w,
    const float* __restrict__ att_b, float* __restrict__ ef2,
    float* __restrict__ w, int e_count) {
  __shared__ float th[D * D];
  for (int i = threadIdx.x * 4; i < D * D; i += 256 * 4) {
    *(float4*)&th[i] = *(const float4*)&theta[i];
  }
  __syncthreads();
  int row = blockIdx.x * 4 + (threadIdx.x >> 6);
  if (row >= e_count) return;
  int lane = threadIdx.x & 63;
  int col = lane * 2;
  float2 xv = *(const float2*)&xm3[(size_t)row * D + col];
  float ax = 0.f, ay = 0.f;
#pragma unroll 8
  for (int j = 0; j < 64; ++j) {
    float x0 = __shfl(xv.x, j);
    float x1 = __shfl(xv.y, j);
    float2 t0 = *(float2*)&th[(2 * j) * D + col];
    float2 t1 = *(float2*)&th[(2 * j + 1) * D + col];
    ax = fmaf(x1, t1.x, fmaf(x0, t0.x, ax));
    ay = fmaf(x1, t1.y, fmaf(x0, t0.y, ay));
  }
  float2 b = *(const float2*)&bias[col];
  ax += b.x; ay += b.y;
  float2 o; o.x = ax; o.y = ay;
  *(float2*)&ef2[(size_t)row * D + col] = o;
  float2 aw = *(const float2*)&att_w[col];
  float part = ax * aw.x + ay * aw.y;
#pragma unroll
  for (int offd = 32; offd > 0; offd >>= 1) part += __shfl_xor(part, offd);
  if (lane == 0) w[row] = 1.0f / (1.0f + expf(-(part + att_b[0])));
}

// ====== final: out[v] = sum_e w[e]*ef2[e] / max(sum_e w[e], 1e-12) ======
__global__ __launch_bounds__(256) void gather_weighted_kernel(
    const float* __restrict__ ef, const float* __restrict__ w,
    const int* __restrict__ off, const int* __restrict__ list,
    float* __restrict__ out, int nseg) {
  int seg = blockIdx.x * 4 + (threadIdx.x >> 6);
  if (seg >= nseg) return;
  int lane = threadIdx.x & 63;
  int col = lane * 2;
  int s0 = off[seg], s1 = off[seg + 1];
  float ax = 0.f, ay = 0.f, wsum = 0.f;
  for (int base = s0; base < s1; base += 64) {
    int m = base + lane;
    int myidx = (m < s1) ? list[m] : 0;
    float myw = (m < s1) ? w[myidx] : 0.f;
    int cnt = min(64, s1 - base);
    int j = 0;
    for (; j + 2 <= cnt; j += 2) {
      int r0 = __shfl(myidx, j + 0);
      int r1 = __shfl(myidx, j + 1);
      float w0 = __shfl(myw, j + 0);
      float w1 = __shfl(myw, j + 1);
      float2 v0 = *(const float2*)&ef[(size_t)r0 * D + col];
      float2 v1 = *(const float2*)&ef[(size_t)r1 * D + col];
      ax = fmaf(w0, v0.x, ax); ay = fmaf(w0, v0.y, ay);
      ax = fmaf(w1, v1.x, ax); ay = fmaf(w1, v1.y, ay);
      wsum += w0 + w1;
    }
    for (; j < cnt; ++j) {
      int r = __shfl(myidx, j);
      float w0 = __shfl(myw, j);
      float2 v = *(const float2*)&ef[(size_t)r * D + col];
      ax = fmaf(w0, v.x, ax); ay = fmaf(w0, v.y, ay);
      wsum += w0;
    }
  }
  float invd = 1.0f / fmaxf(wsum, 1e-12f);
  float2 o; o.x = ax * invd; o.y = ay * invd;
  *(float2*)&out[(size_t)seg * D + col] = o;
}

extern "C" void kernel_launch(void* const* d_in, const int* in_sizes, int n_in,
                              void* d_out, int out_size, void* d_ws, size_t ws_size,
                              hipStream_t stream) {
  const float* x        = (const float*)d_in[0];
  const float* theta    = (const float*)d_in[1];
  const float* bias     = (const float*)d_in[2];
  const float* att_w    = (const float*)d_in[3];
  const float* att_b    = (const float*)d_in[4];
  const int*   node_idx = (const int*)d_in[5];
  const int*   edge_idx = (const int*)d_in[6];
  int n   = in_sizes[0] / D;   // 100000
  int nnz = in_sizes[5];       // 800000
  int E   = EDGES;             // 25000
  float* out = (float*)d_out;

  // ---- workspace layout ----
  char* p = (char*)d_ws;
  float* xm1 = (float*)p;           p += (size_t)E * D * sizeof(float);
  float* xm3 = (float*)p;           p += (size_t)E * D * sizeof(float);
  float* ef2 = (float*)p;           p += (size_t)E * D * sizeof(float);
  float* w   = (float*)p;           p += (size_t)E * sizeof(float);
  int* e_off   = (int*)p;           p += (size_t)(E + 1) * sizeof(int);
  int* n_off   = (int*)p;           p += (size_t)(n + 1) * sizeof(int);
  int* e_nodes = (int*)p;           p += (size_t)nnz * sizeof(int);
  int* n_edges = (int*)p;           p += (size_t)nnz * sizeof(int);
  int* ecnt    = (int*)p;           p += (size_t)E * sizeof(int);   // also cursor
  int* ncnt    = (int*)p;           p += (size_t)n * sizeof(int);   // also cursor
  int* bsum    = (int*)p;           p += 1024 * sizeof(int);
  int* dummy   = (int*)p;           p += 64 * sizeof(int);
  float* xm2 = out;                 // N x D scratch; fully overwritten by final gather

  int nb_e = (E + 1023) / 1024;    // 25
  int nb_n = (n + 1023) / 1024;    // 98

  // ---- CSR build ----
  hipMemsetAsync(ecnt, 0, ((size_t)E + n) * sizeof(int), stream);
  hist_kernel<<<(nnz + 255) / 256, 256, 0, stream>>>(node_idx, edge_idx, ncnt, ecnt, nnz);

  scan_block_kernel<<<nb_e, 256, 0, stream>>>(ecnt, e_off, bsum, E);
  scan_block_kernel<<<1, 256, 0, stream>>>(bsum, bsum, dummy, nb_e);
  scan_add_kernel<<<(E + 255) / 256, 256, 0, stream>>>(e_off, bsum, ecnt, E);

  scan_block_kernel<<<nb_n, 256, 0, stream>>>(ncnt, n_off, bsum, n);
  scan_block_kernel<<<1, 256, 0, stream>>>(bsum, bsum, dummy, nb_n);
  scan_add_kernel<<<(n + 255) / 256, 256, 0, stream>>>(n_off, bsum, ncnt, n);

  hipMemsetAsync(ecnt, 0, ((size_t)E + n) * sizeof(int), stream);  // cursors
  fill_kernel<<<(nnz + 255) / 256, 256, 0, stream>>>(
      node_idx, edge_idx, e_off, n_off, ecnt, ncnt, e_nodes, n_edges, nnz);

  // ---- 1) xm1[e] = mean over edge members of x ----
  gather_mean_kernel<<<(E + 3) / 4, 256, 0, stream>>>(x, e_off, e_nodes, xm1, E);

  // ---- 2) xm2[v] = mean over node's incident edges of xm1 (stored in d_out) ----
  gather_mean_kernel<<<(n + 3) / 4, 256, 0, stream>>>(xm1, n_off, n_edges, xm2, n);

  // ---- 3) xm3[e] = mean over edge members of xm2 ----
  gather_mean_kernel<<<(E + 3) / 4, 256, 0, stream>>>(xm2, e_off, e_nodes, xm3, E);

  // ---- 4) ef2 = xm3@theta + bias; w = sigmoid(ef2 @ att_w + att_b) ----
  gemm_att_kernel<<<(E + 3) / 4, 256, 0, stream>>>(
      xm3, theta, bias, att_w, att_b, ef2, w, E);

  // ---- 5) out[v] = weighted mean of ef2 over v's incident edges ----
  gather_weighted_kernel<<<(n + 3) / 4, 256, 0, stream>>>(ef2, w, n_off, n_edges, out, n);
}

// Round 5
// 486.073 us; speedup vs baseline: 11.7508x; 1.0148x over previous
//
#include <hip/hip_runtime.h>

#define D 128
#define EDGES 25000
#define NSLICE 8

// ================= sliced histogram (scalar, grid-stride) =================
// Each slice's blocks stream ALL pairs but count only destinations in the
// slice's id-range -> counter lines are touched by one XCD only.
__global__ __launch_bounds__(256) void hist_sliced_kernel(
    const int* __restrict__ nidx, const int* __restrict__ eidx,
    int* __restrict__ ncnt, int* __restrict__ ecnt, int nnz, int n) {
  int slice = blockIdx.x & (NSLICE - 1);
  int bid = blockIdx.x >> 3;                 // block index within slice
  int bps = gridDim.x >> 3;                  // blocks per slice
  int elo = EDGES * slice / NSLICE, ehi = EDGES * (slice + 1) / NSLICE;
  int nlo = (int)((long long)n * slice / NSLICE);
  int nhi = (int)((long long)n * (slice + 1) / NSLICE);
  for (int p = bid * 256 + threadIdx.x; p < nnz; p += bps * 256) {
    int e = eidx[p], v = nidx[p];
    if (e >= elo && e < ehi) atomicAdd(&ecnt[e], 1);
    if (v >= nlo && v < nhi) atomicAdd(&ncnt[v], 1);
  }
}

// exclusive scan, 1024 elems per block (4/thread), Hillis-Steele in LDS
__global__ __launch_bounds__(256) void scan_block_kernel(
    const int* __restrict__ in, int* __restrict__ out, int* __restrict__ bsum, int n) {
  __shared__ int s[256];
  int t = threadIdx.x;
  int base = blockIdx.x * 1024 + t * 4;
  int c0 = (base + 0 < n) ? in[base + 0] : 0;
  int c1 = (base + 1 < n) ? in[base + 1] : 0;
  int c2 = (base + 2 < n) ? in[base + 2] : 0;
  int c3 = (base + 3 < n) ? in[base + 3] : 0;
  int lsum = c0 + c1 + c2 + c3;
  s[t] = lsum;
  __syncthreads();
  for (int off = 1; off < 256; off <<= 1) {
    int a = (t >= off) ? s[t - off] : 0;
    __syncthreads();
    s[t] += a;
    __syncthreads();
  }
  int excl = s[t] - lsum;
  if (base + 0 < n) out[base + 0] = excl;
  if (base + 1 < n) out[base + 1] = excl + c0;
  if (base + 2 < n) out[base + 2] = excl + c0 + c1;
  if (base + 3 < n) out[base + 3] = excl + c0 + c1 + c2;
  if (t == 255) bsum[blockIdx.x] = s[255];
}

__global__ __launch_bounds__(256) void scan_add_kernel(
    int* __restrict__ out, const int* __restrict__ bsum,
    const int* __restrict__ cnt, int n) {
  int i = blockIdx.x * 256 + threadIdx.x;
  if (i >= n) return;
  int v = out[i] + bsum[i >> 10];
  out[i] = v;
  if (i == n - 1) out[n] = v + cnt[i];
}

// ================= sliced fill (scalar, grid-stride) =================
__global__ __launch_bounds__(256) void fill_sliced_kernel(
    const int* __restrict__ nidx, const int* __restrict__ eidx,
    const int* __restrict__ e_off, const int* __restrict__ n_off,
    int* __restrict__ ecur, int* __restrict__ ncur,
    int* __restrict__ e_nodes, int* __restrict__ n_edges, int nnz, int n) {
  int slice = blockIdx.x & (NSLICE - 1);
  int bid = blockIdx.x >> 3;
  int bps = gridDim.x >> 3;
  int elo = EDGES * slice / NSLICE, ehi = EDGES * (slice + 1) / NSLICE;
  int nlo = (int)((long long)n * slice / NSLICE);
  int nhi = (int)((long long)n * (slice + 1) / NSLICE);
  for (int p = bid * 256 + threadIdx.x; p < nnz; p += bps * 256) {
    int v = nidx[p], e = eidx[p];
    if (e >= elo && e < ehi) {
      int pe = e_off[e] + atomicAdd(&ecur[e], 1);
      e_nodes[pe] = v;
    }
    if (v >= nlo && v < nhi) {
      int pn = n_off[v] + atomicAdd(&ncur[v], 1);
      n_edges[pn] = e;
    }
  }
}

// ================= segment-mean gather: one wave per segment =================
__global__ __launch_bounds__(256) void gather_mean_kernel(
    const float* __restrict__ src, const int* __restrict__ off,
    const int* __restrict__ list, float* __restrict__ dst, int nseg) {
  int seg = blockIdx.x * 4 + (threadIdx.x >> 6);
  if (seg >= nseg) return;
  int lane = threadIdx.x & 63;
  int col = lane * 2;
  int s0 = off[seg], s1 = off[seg + 1];
  float ax = 0.f, ay = 0.f;
  for (int base = s0; base < s1; base += 64) {
    int m = base + lane;
    int myidx = (m < s1) ? list[m] : 0;
    int cnt = min(64, s1 - base);
    int j = 0;
    for (; j + 4 <= cnt; j += 4) {
      int r0 = __shfl(myidx, j + 0);
      int r1 = __shfl(myidx, j + 1);
      int r2 = __shfl(myidx, j + 2);
      int r3 = __shfl(myidx, j + 3);
      float2 v0 = *(const float2*)&src[(size_t)r0 * D + col];
      float2 v1 = *(const float2*)&src[(size_t)r1 * D + col];
      float2 v2 = *(const float2*)&src[(size_t)r2 * D + col];
      float2 v3 = *(const float2*)&src[(size_t)r3 * D + col];
      ax += v0.x + v1.x + v2.x + v3.x;
      ay += v0.y + v1.y + v2.y + v3.y;
    }
    for (; j < cnt; ++j) {
      int r = __shfl(myidx, j);
      float2 v = *(const float2*)&src[(size_t)r * D + col];
      ax += v.x; ay += v.y;
    }
  }
  float inv = 1.0f / fmaxf((float)(s1 - s0), 1.0f);
  float2 o; o.x = ax * inv; o.y = ay * inv;
  *(float2*)&dst[(size_t)seg * D + col] = o;
}

// ====== fused small GEMM + attention: ef2 = xm3@theta + bias, w = sigmoid(ef2.att_w+att_b)
__global__ __launch_bounds__(256) void gemm_att_kernel(
    const float* __restrict__ xm3, const float* __restrict__ theta,
    const float* __restrict__ bias, const float* __restrict__ att_w,
    const float* __restrict__ att_b, float* __restrict__ ef2,
    float* __restrict__ w, int e_count) {
  __shared__ float th[D * D];
  for (int i = threadIdx.x * 4; i < D * D; i += 256 * 4) {
    *(float4*)&th[i] = *(const float4*)&theta[i];
  }
  __syncthreads();
  int row = blockIdx.x * 4 + (threadIdx.x >> 6);
  if (row >= e_count) return;
  int lane = threadIdx.x & 63;
  int col = lane * 2;
  float2 xv = *(const float2*)&xm3[(size_t)row * D + col];
  float ax = 0.f, ay = 0.f;
#pragma unroll 8
  for (int j = 0; j < 64; ++j) {
    float x0 = __shfl(xv.x, j);
    float x1 = __shfl(xv.y, j);
    float2 t0 = *(float2*)&th[(2 * j) * D + col];
    float2 t1 = *(float2*)&th[(2 * j + 1) * D + col];
    ax = fmaf(x1, t1.x, fmaf(x0, t0.x, ax));
    ay = fmaf(x1, t1.y, fmaf(x0, t0.y, ay));
  }
  float2 b = *(const float2*)&bias[col];
  ax += b.x; ay += b.y;
  float2 o; o.x = ax; o.y = ay;
  *(float2*)&ef2[(size_t)row * D + col] = o;
  float2 aw = *(const float2*)&att_w[col];
  float part = ax * aw.x + ay * aw.y;
#pragma unroll
  for (int offd = 32; offd > 0; offd >>= 1) part += __shfl_xor(part, offd);
  if (lane == 0) w[row] = 1.0f / (1.0f + expf(-(part + att_b[0])));
}

// ====== final: out[v] = sum_e w[e]*ef2[e] / max(sum_e w[e], 1e-12) ======
__global__ __launch_bounds__(256) void gather_weighted_kernel(
    const float* __restrict__ ef, const float* __restrict__ w,
    const int* __restrict__ off, const int* __restrict__ list,
    float* __restrict__ out, int nseg) {
  int seg = blockIdx.x * 4 + (threadIdx.x >> 6);
  if (seg >= nseg) return;
  int lane = threadIdx.x & 63;
  int col = lane * 2;
  int s0 = off[seg], s1 = off[seg + 1];
  float ax = 0.f, ay = 0.f, wsum = 0.f;
  for (int base = s0; base < s1; base += 64) {
    int m = base + lane;
    int myidx = (m < s1) ? list[m] : 0;
    float myw = (m < s1) ? w[myidx] : 0.f;
    int cnt = min(64, s1 - base);
    int j = 0;
    for (; j + 2 <= cnt; j += 2) {
      int r0 = __shfl(myidx, j + 0);
      int r1 = __shfl(myidx, j + 1);
      float w0 = __shfl(myw, j + 0);
      float w1 = __shfl(myw, j + 1);
      float2 v0 = *(const float2*)&ef[(size_t)r0 * D + col];
      float2 v1 = *(const float2*)&ef[(size_t)r1 * D + col];
      ax = fmaf(w0, v0.x, ax); ay = fmaf(w0, v0.y, ay);
      ax = fmaf(w1, v1.x, ax); ay = fmaf(w1, v1.y, ay);
      wsum += w0 + w1;
    }
    for (; j < cnt; ++j) {
      int r = __shfl(myidx, j);
      float w0 = __shfl(myw, j);
      float2 v = *(const float2*)&ef[(size_t)r * D + col];
      ax = fmaf(w0, v.x, ax); ay = fmaf(w0, v.y, ay);
      wsum += w0;
    }
  }
  float invd = 1.0f / fmaxf(wsum, 1e-12f);
  float2 o; o.x = ax * invd; o.y = ay * invd;
  *(float2*)&out[(size_t)seg * D + col] = o;
}

extern "C" void kernel_launch(void* const* d_in, const int* in_sizes, int n_in,
                              void* d_out, int out_size, void* d_ws, size_t ws_size,
                              hipStream_t stream) {
  const float* x        = (const float*)d_in[0];
  const float* theta    = (const float*)d_in[1];
  const float* bias     = (const float*)d_in[2];
  const float* att_w    = (const float*)d_in[3];
  const float* att_b    = (const float*)d_in[4];
  const int*   node_idx = (const int*)d_in[5];
  const int*   edge_idx = (const int*)d_in[6];
  int n   = in_sizes[0] / D;   // 100000
  int nnz = in_sizes[5];       // 800000
  int E   = EDGES;             // 25000
  float* out = (float*)d_out;

  // ---- workspace layout ----
  char* p = (char*)d_ws;
  float* xm1 = (float*)p;           p += (size_t)E * D * sizeof(float);
  float* xm3 = (float*)p;           p += (size_t)E * D * sizeof(float);
  float* ef2 = (float*)p;           p += (size_t)E * D * sizeof(float);
  float* w   = (float*)p;           p += (size_t)E * sizeof(float);
  int* e_off   = (int*)p;           p += (size_t)(E + 1) * sizeof(int);
  int* n_off   = (int*)p;           p += (size_t)(n + 1) * sizeof(int);
  int* e_nodes = (int*)p;           p += (size_t)nnz * sizeof(int);
  int* n_edges = (int*)p;           p += (size_t)nnz * sizeof(int);
  int* ecnt    = (int*)p;           p += (size_t)E * sizeof(int);   // also cursor
  int* ncnt    = (int*)p;           p += (size_t)n * sizeof(int);   // also cursor
  int* bsum    = (int*)p;           p += 1024 * sizeof(int);
  int* dummy   = (int*)p;           p += 64 * sizeof(int);
  float* xm2 = out;                 // N x D scratch; fully overwritten by final gather

  int nb_e = (E + 1023) / 1024;    // 25
  int nb_n = (n + 1023) / 1024;    // 98
  int sliced_grid = 256 * NSLICE;  // 2048 blocks, 256 per slice

  // ---- CSR build ----
  hipMemsetAsync(ecnt, 0, ((size_t)E + n) * sizeof(int), stream);
  hist_sliced_kernel<<<sliced_grid, 256, 0, stream>>>(node_idx, edge_idx, ncnt, ecnt, nnz, n);

  scan_block_kernel<<<nb_e, 256, 0, stream>>>(ecnt, e_off, bsum, E);
  scan_block_kernel<<<1, 256, 0, stream>>>(bsum, bsum, dummy, nb_e);
  scan_add_kernel<<<(E + 255) / 256, 256, 0, stream>>>(e_off, bsum, ecnt, E);

  scan_block_kernel<<<nb_n, 256, 0, stream>>>(ncnt, n_off, bsum, n);
  scan_block_kernel<<<1, 256, 0, stream>>>(bsum, bsum, dummy, nb_n);
  scan_add_kernel<<<(n + 255) / 256, 256, 0, stream>>>(n_off, bsum, ncnt, n);

  hipMemsetAsync(ecnt, 0, ((size_t)E + n) * sizeof(int), stream);  // cursors
  fill_sliced_kernel<<<sliced_grid, 256, 0, stream>>>(
      node_idx, edge_idx, e_off, n_off, ecnt, ncnt, e_nodes, n_edges, nnz, n);

  // ---- 1) xm1[e] = mean over edge members of x ----
  gather_mean_kernel<<<(E + 3) / 4, 256, 0, stream>>>(x, e_off, e_nodes, xm1, E);

  // ---- 2) xm2[v] = mean over node's incident edges of xm1 (stored in d_out) ----
  gather_mean_kernel<<<(n + 3) / 4, 256, 0, stream>>>(xm1, n_off, n_edges, xm2, n);

  // ---- 3) xm3[e] = mean over edge members of xm2 ----
  gather_mean_kernel<<<(E + 3) / 4, 256, 0, stream>>>(xm2, e_off, e_nodes, xm3, E);

  // ---- 4) ef2 = xm3@theta + bias; w = sigmoid(ef2 @ att_w + att_b) ----
  gemm_att_kernel<<<(E + 3) / 4, 256, 0, stream>>>(
      xm3, theta, bias, att_w, att_b, ef2, w, E);

  // ---- 5) out[v] = weighted mean of ef2 over v's incident edges ----
  gather_weighted_kernel<<<(n + 3) / 4, 256, 0, stream>>>(ef2, w, n_off, n_edges, out, n);
}

// Round 6
// 434.872 us; speedup vs baseline: 13.1343x; 1.1177x over previous
//
#include <hip/hip_runtime.h>

#define D 128
#define EDGES 25000
#define NSLICE 8

// ================= sliced histogram (scalar, grid-stride) =================
__global__ __launch_bounds__(256) void hist_sliced_kernel(
    const int* __restrict__ nidx, const int* __restrict__ eidx,
    int* __restrict__ ncnt, int* __restrict__ ecnt, int nnz, int n) {
  int slice = blockIdx.x & (NSLICE - 1);
  int bid = blockIdx.x >> 3;                 // block index within slice
  int bps = gridDim.x >> 3;                  // blocks per slice
  int elo = EDGES * slice / NSLICE, ehi = EDGES * (slice + 1) / NSLICE;
  int nlo = (int)((long long)n * slice / NSLICE);
  int nhi = (int)((long long)n * (slice + 1) / NSLICE);
  for (int p = bid * 256 + threadIdx.x; p < nnz; p += bps * 256) {
    int e = eidx[p], v = nidx[p];
    if (e >= elo && e < ehi) atomicAdd(&ecnt[e], 1);
    if (v >= nlo && v < nhi) atomicAdd(&ncnt[v], 1);
  }
}

// exclusive scan, 1024 elems per block (4/thread), Hillis-Steele in LDS
__global__ __launch_bounds__(256) void scan_block_kernel(
    const int* __restrict__ in, int* __restrict__ out, int* __restrict__ bsum, int n) {
  __shared__ int s[256];
  int t = threadIdx.x;
  int base = blockIdx.x * 1024 + t * 4;
  int c0 = (base + 0 < n) ? in[base + 0] : 0;
  int c1 = (base + 1 < n) ? in[base + 1] : 0;
  int c2 = (base + 2 < n) ? in[base + 2] : 0;
  int c3 = (base + 3 < n) ? in[base + 3] : 0;
  int lsum = c0 + c1 + c2 + c3;
  s[t] = lsum;
  __syncthreads();
  for (int off = 1; off < 256; off <<= 1) {
    int a = (t >= off) ? s[t - off] : 0;
    __syncthreads();
    s[t] += a;
    __syncthreads();
  }
  int excl = s[t] - lsum;
  if (base + 0 < n) out[base + 0] = excl;
  if (base + 1 < n) out[base + 1] = excl + c0;
  if (base + 2 < n) out[base + 2] = excl + c0 + c1;
  if (base + 3 < n) out[base + 3] = excl + c0 + c1 + c2;
  if (t == 255) bsum[blockIdx.x] = s[255];
}

__global__ __launch_bounds__(256) void scan_add_kernel(
    int* __restrict__ out, const int* __restrict__ bsum,
    const int* __restrict__ cnt, int n) {
  int i = blockIdx.x * 256 + threadIdx.x;
  if (i >= n) return;
  int v = out[i] + bsum[i >> 10];
  out[i] = v;
  if (i == n - 1) out[n] = v + cnt[i];
}

// ================= sliced fill (scalar, grid-stride) =================
__global__ __launch_bounds__(256) void fill_sliced_kernel(
    const int* __restrict__ nidx, const int* __restrict__ eidx,
    const int* __restrict__ e_off, const int* __restrict__ n_off,
    int* __restrict__ ecur, int* __restrict__ ncur,
    int* __restrict__ e_nodes, int* __restrict__ n_edges, int nnz, int n) {
  int slice = blockIdx.x & (NSLICE - 1);
  int bid = blockIdx.x >> 3;
  int bps = gridDim.x >> 3;
  int elo = EDGES * slice / NSLICE, ehi = EDGES * (slice + 1) / NSLICE;
  int nlo = (int)((long long)n * slice / NSLICE);
  int nhi = (int)((long long)n * (slice + 1) / NSLICE);
  for (int p = bid * 256 + threadIdx.x; p < nnz; p += bps * 256) {
    int v = nidx[p], e = eidx[p];
    if (e >= elo && e < ehi) {
      int pe = e_off[e] + atomicAdd(&ecur[e], 1);
      e_nodes[pe] = v;
    }
    if (v >= nlo && v < nhi) {
      int pn = n_off[v] + atomicAdd(&ncur[v], 1);
      n_edges[pn] = e;
    }
  }
}

// ================= segment-mean gather: one wave per segment =================
__global__ __launch_bounds__(256) void gather_mean_kernel(
    const float* __restrict__ src, const int* __restrict__ off,
    const int* __restrict__ list, float* __restrict__ dst, int nseg) {
  int seg = blockIdx.x * 4 + (threadIdx.x >> 6);
  if (seg >= nseg) return;
  int lane = threadIdx.x & 63;
  int col = lane * 2;
  int s0 = off[seg], s1 = off[seg + 1];
  float ax = 0.f, ay = 0.f;
  for (int base = s0; base < s1; base += 64) {
    int m = base + lane;
    int myidx = (m < s1) ? list[m] : 0;
    int cnt = min(64, s1 - base);
    int j = 0;
    for (; j + 4 <= cnt; j += 4) {
      int r0 = __shfl(myidx, j + 0);
      int r1 = __shfl(myidx, j + 1);
      int r2 = __shfl(myidx, j + 2);
      int r3 = __shfl(myidx, j + 3);
      float2 v0 = *(const float2*)&src[(size_t)r0 * D + col];
      float2 v1 = *(const float2*)&src[(size_t)r1 * D + col];
      float2 v2 = *(const float2*)&src[(size_t)r2 * D + col];
      float2 v3 = *(const float2*)&src[(size_t)r3 * D + col];
      ax += v0.x + v1.x + v2.x + v3.x;
      ay += v0.y + v1.y + v2.y + v3.y;
    }
    for (; j < cnt; ++j) {
      int r = __shfl(myidx, j);
      float2 v = *(const float2*)&src[(size_t)r * D + col];
      ax += v.x; ay += v.y;
    }
  }
  float inv = 1.0f / fmaxf((float)(s1 - s0), 1.0f);
  float2 o; o.x = ax * inv; o.y = ay * inv;
  *(float2*)&dst[(size_t)seg * D + col] = o;
}

// ====== register-tiled GEMM + fused attention (no LDS) ======
// 256 threads = 8 row-groups x 32 col-groups; each thread: 4 rows x 4 cols.
// ef2 = xm3@theta + bias;  w = sigmoid(ef2 @ att_w + att_b)
__device__ inline float4 f4fma(float s, float4 b, float4 acc) {
  acc.x = fmaf(s, b.x, acc.x); acc.y = fmaf(s, b.y, acc.y);
  acc.z = fmaf(s, b.z, acc.z); acc.w = fmaf(s, b.w, acc.w);
  return acc;
}

__global__ __launch_bounds__(256) void gemm_att_kernel(
    const float* __restrict__ xm3, const float* __restrict__ theta,
    const float* __restrict__ bias, const float* __restrict__ att_w,
    const float* __restrict__ att_b, float* __restrict__ ef2,
    float* __restrict__ w, int e_count) {
  int tid = threadIdx.x;
  int cg = tid & 31;            // col group: cols cg*4 .. +3
  int rg = tid >> 5;            // row group: rows row0 .. +3
  int row0 = blockIdx.x * 32 + rg * 4;
  int c0 = cg * 4;

  const float* ap[4];
#pragma unroll
  for (int r = 0; r < 4; ++r) {
    int rr = min(row0 + r, e_count - 1);
    ap[r] = xm3 + (size_t)rr * D;
  }

  float4 acc[4];
#pragma unroll
  for (int r = 0; r < 4; ++r) acc[r] = make_float4(0.f, 0.f, 0.f, 0.f);

#pragma unroll 2
  for (int k = 0; k < D; k += 4) {
    float4 b0 = *(const float4*)&theta[(k + 0) * D + c0];
    float4 b1 = *(const float4*)&theta[(k + 1) * D + c0];
    float4 b2 = *(const float4*)&theta[(k + 2) * D + c0];
    float4 b3 = *(const float4*)&theta[(k + 3) * D + c0];
#pragma unroll
    for (int r = 0; r < 4; ++r) {
      float4 a = *(const float4*)(ap[r] + k);
      acc[r] = f4fma(a.x, b0, acc[r]);
      acc[r] = f4fma(a.y, b1, acc[r]);
      acc[r] = f4fma(a.z, b2, acc[r]);
      acc[r] = f4fma(a.w, b3, acc[r]);
    }
  }

  float4 bv = *(const float4*)&bias[c0];
  float4 awv = *(const float4*)&att_w[c0];
  float ab = att_b[0];
  float part[4];
#pragma unroll
  for (int r = 0; r < 4; ++r) {
    acc[r].x += bv.x; acc[r].y += bv.y; acc[r].z += bv.z; acc[r].w += bv.w;
    part[r] = acc[r].x * awv.x + acc[r].y * awv.y +
              acc[r].z * awv.z + acc[r].w * awv.w;
  }
  // reduce attention partials across the 32 col-group lanes
#pragma unroll
  for (int off = 16; off >= 1; off >>= 1) {
#pragma unroll
    for (int r = 0; r < 4; ++r) part[r] += __shfl_xor(part[r], off);
  }
#pragma unroll
  for (int r = 0; r < 4; ++r) {
    if (row0 + r < e_count)
      *(float4*)&ef2[(size_t)(row0 + r) * D + c0] = acc[r];
  }
  if (cg == 0) {
    float s[4];
#pragma unroll
    for (int r = 0; r < 4; ++r) s[r] = 1.0f / (1.0f + expf(-(part[r] + ab)));
    if (row0 + 3 < e_count) {
      *(float4*)&w[row0] = make_float4(s[0], s[1], s[2], s[3]);
    } else {
#pragma unroll
      for (int r = 0; r < 4; ++r)
        if (row0 + r < e_count) w[row0 + r] = s[r];
    }
  }
}

// ====== final: out[v] = sum_e w[e]*ef2[e] / max(sum_e w[e], 1e-12) ======
__global__ __launch_bounds__(256) void gather_weighted_kernel(
    const float* __restrict__ ef, const float* __restrict__ w,
    const int* __restrict__ off, const int* __restrict__ list,
    float* __restrict__ out, int nseg) {
  int seg = blockIdx.x * 4 + (threadIdx.x >> 6);
  if (seg >= nseg) return;
  int lane = threadIdx.x & 63;
  int col = lane * 2;
  int s0 = off[seg], s1 = off[seg + 1];
  float ax = 0.f, ay = 0.f, wsum = 0.f;
  for (int base = s0; base < s1; base += 64) {
    int m = base + lane;
    int myidx = (m < s1) ? list[m] : 0;
    float myw = (m < s1) ? w[myidx] : 0.f;
    int cnt = min(64, s1 - base);
    int j = 0;
    for (; j + 2 <= cnt; j += 2) {
      int r0 = __shfl(myidx, j + 0);
      int r1 = __shfl(myidx, j + 1);
      float w0 = __shfl(myw, j + 0);
      float w1 = __shfl(myw, j + 1);
      float2 v0 = *(const float2*)&ef[(size_t)r0 * D + col];
      float2 v1 = *(const float2*)&ef[(size_t)r1 * D + col];
      ax = fmaf(w0, v0.x, ax); ay = fmaf(w0, v0.y, ay);
      ax = fmaf(w1, v1.x, ax); ay = fmaf(w1, v1.y, ay);
      wsum += w0 + w1;
    }
    for (; j < cnt; ++j) {
      int r = __shfl(myidx, j);
      float w0 = __shfl(myw, j);
      float2 v = *(const float2*)&ef[(size_t)r * D + col];
      ax = fmaf(w0, v.x, ax); ay = fmaf(w0, v.y, ay);
      wsum += w0;
    }
  }
  float invd = 1.0f / fmaxf(wsum, 1e-12f);
  float2 o; o.x = ax * invd; o.y = ay * invd;
  *(float2*)&out[(size_t)seg * D + col] = o;
}

extern "C" void kernel_launch(void* const* d_in, const int* in_sizes, int n_in,
                              void* d_out, int out_size, void* d_ws, size_t ws_size,
                              hipStream_t stream) {
  const float* x        = (const float*)d_in[0];
  const float* theta    = (const float*)d_in[1];
  const float* bias     = (const float*)d_in[2];
  const float* att_w    = (const float*)d_in[3];
  const float* att_b    = (const float*)d_in[4];
  const int*   node_idx = (const int*)d_in[5];
  const int*   edge_idx = (const int*)d_in[6];
  int n   = in_sizes[0] / D;   // 100000
  int nnz = in_sizes[5];       // 800000
  int E   = EDGES;             // 25000
  float* out = (float*)d_out;

  // ---- workspace layout ----
  char* p = (char*)d_ws;
  float* xm1 = (float*)p;           p += (size_t)E * D * sizeof(float);
  float* xm3 = (float*)p;           p += (size_t)E * D * sizeof(float);
  float* ef2 = (float*)p;           p += (size_t)E * D * sizeof(float);
  float* w   = (float*)p;           p += (size_t)E * sizeof(float);
  int* e_off   = (int*)p;           p += (size_t)(E + 1) * sizeof(int);
  int* n_off   = (int*)p;           p += (size_t)(n + 1) * sizeof(int);
  int* e_nodes = (int*)p;           p += (size_t)nnz * sizeof(int);
  int* n_edges = (int*)p;           p += (size_t)nnz * sizeof(int);
  int* ecnt    = (int*)p;           p += (size_t)E * sizeof(int);   // also cursor
  int* ncnt    = (int*)p;           p += (size_t)n * sizeof(int);   // also cursor
  int* bsum    = (int*)p;           p += 1024 * sizeof(int);
  int* dummy   = (int*)p;           p += 64 * sizeof(int);
  float* xm2 = out;                 // N x D scratch; fully overwritten by final gather

  int nb_e = (E + 1023) / 1024;    // 25
  int nb_n = (n + 1023) / 1024;    // 98
  int sliced_grid = 256 * NSLICE;  // 2048 blocks, 256 per slice

  // ---- CSR build ----
  hipMemsetAsync(ecnt, 0, ((size_t)E + n) * sizeof(int), stream);
  hist_sliced_kernel<<<sliced_grid, 256, 0, stream>>>(node_idx, edge_idx, ncnt, ecnt, nnz, n);

  scan_block_kernel<<<nb_e, 256, 0, stream>>>(ecnt, e_off, bsum, E);
  scan_block_kernel<<<1, 256, 0, stream>>>(bsum, bsum, dummy, nb_e);
  scan_add_kernel<<<(E + 255) / 256, 256, 0, stream>>>(e_off, bsum, ecnt, E);

  scan_block_kernel<<<nb_n, 256, 0, stream>>>(ncnt, n_off, bsum, n);
  scan_block_kernel<<<1, 256, 0, stream>>>(bsum, bsum, dummy, nb_n);
  scan_add_kernel<<<(n + 255) / 256, 256, 0, stream>>>(n_off, bsum, ncnt, n);

  hipMemsetAsync(ecnt, 0, ((size_t)E + n) * sizeof(int), stream);  // cursors
  fill_sliced_kernel<<<sliced_grid, 256, 0, stream>>>(
      node_idx, edge_idx, e_off, n_off, ecnt, ncnt, e_nodes, n_edges, nnz, n);

  // ---- 1) xm1[e] = mean over edge members of x ----
  gather_mean_kernel<<<(E + 3) / 4, 256, 0, stream>>>(x, e_off, e_nodes, xm1, E);

  // ---- 2) xm2[v] = mean over node's incident edges of xm1 (stored in d_out) ----
  gather_mean_kernel<<<(n + 3) / 4, 256, 0, stream>>>(xm1, n_off, n_edges, xm2, n);

  // ---- 3) xm3[e] = mean over edge members of xm2 ----
  gather_mean_kernel<<<(E + 3) / 4, 256, 0, stream>>>(xm2, e_off, e_nodes, xm3, E);

  // ---- 4) ef2 = xm3@theta + bias; w = sigmoid(ef2 @ att_w + att_b) ----
  gemm_att_kernel<<<(E + 31) / 32, 256, 0, stream>>>(
      xm3, theta, bias, att_w, att_b, ef2, w, E);

  // ---- 5) out[v] = weighted mean of ef2 over v's incident edges ----
  gather_weighted_kernel<<<(n + 3) / 4, 256, 0, stream>>>(ef2, w, n_off, n_edges, out, n);
}

// Round 7
// 373.203 us; speedup vs baseline: 15.3047x; 1.1652x over previous
//
#include <hip/hip_runtime.h>

#define D 128
#define EDGES 25000
#define NSLICE 8

// ---------------- bf16 helpers (round-to-nearest-even) ----------------
__device__ inline float bf2f(unsigned short h) {
  return __uint_as_float(((unsigned)h) << 16);
}
__device__ inline unsigned short f2bf(float f) {
  unsigned u = __float_as_uint(f);
  u += 0x7FFFu + ((u >> 16) & 1u);
  return (unsigned short)(u >> 16);
}
__device__ inline float2 load2(const float* p) { return *(const float2*)p; }
__device__ inline float2 load2(const unsigned short* p) {
  ushort2 u = *(const ushort2*)p;
  float2 v; v.x = bf2f(u.x); v.y = bf2f(u.y);
  return v;
}
__device__ inline void store2(float* p, float2 v) { *(float2*)p = v; }
__device__ inline void store2(unsigned short* p, float2 v) {
  ushort2 u; u.x = f2bf(v.x); u.y = f2bf(v.y);
  *(ushort2*)p = u;
}

// ================= sliced histogram (scalar, grid-stride) =================
__global__ __launch_bounds__(256) void hist_sliced_kernel(
    const int* __restrict__ nidx, const int* __restrict__ eidx,
    int* __restrict__ ncnt, int* __restrict__ ecnt, int nnz, int n) {
  int slice = blockIdx.x & (NSLICE - 1);
  int bid = blockIdx.x >> 3;                 // block index within slice
  int bps = gridDim.x >> 3;                  // blocks per slice
  int elo = EDGES * slice / NSLICE, ehi = EDGES * (slice + 1) / NSLICE;
  int nlo = (int)((long long)n * slice / NSLICE);
  int nhi = (int)((long long)n * (slice + 1) / NSLICE);
  for (int p = bid * 256 + threadIdx.x; p < nnz; p += bps * 256) {
    int e = eidx[p], v = nidx[p];
    if (e >= elo && e < ehi) atomicAdd(&ecnt[e], 1);
    if (v >= nlo && v < nhi) atomicAdd(&ncnt[v], 1);
  }
}

// exclusive scan, 1024 elems per block (4/thread), Hillis-Steele in LDS
__global__ __launch_bounds__(256) void scan_block_kernel(
    const int* __restrict__ in, int* __restrict__ out, int* __restrict__ bsum, int n) {
  __shared__ int s[256];
  int t = threadIdx.x;
  int base = blockIdx.x * 1024 + t * 4;
  int c0 = (base + 0 < n) ? in[base + 0] : 0;
  int c1 = (base + 1 < n) ? in[base + 1] : 0;
  int c2 = (base + 2 < n) ? in[base + 2] : 0;
  int c3 = (base + 3 < n) ? in[base + 3] : 0;
  int lsum = c0 + c1 + c2 + c3;
  s[t] = lsum;
  __syncthreads();
  for (int off = 1; off < 256; off <<= 1) {
    int a = (t >= off) ? s[t - off] : 0;
    __syncthreads();
    s[t] += a;
    __syncthreads();
  }
  int excl = s[t] - lsum;
  if (base + 0 < n) out[base + 0] = excl;
  if (base + 1 < n) out[base + 1] = excl + c0;
  if (base + 2 < n) out[base + 2] = excl + c0 + c1;
  if (base + 3 < n) out[base + 3] = excl + c0 + c1 + c2;
  if (t == 255) bsum[blockIdx.x] = s[255];
}

__global__ __launch_bounds__(256) void scan_add_kernel(
    int* __restrict__ out, const int* __restrict__ bsum,
    const int* __restrict__ cnt, int n) {
  int i = blockIdx.x * 256 + threadIdx.x;
  if (i >= n) return;
  int v = out[i] + bsum[i >> 10];
  out[i] = v;
  if (i == n - 1) out[n] = v + cnt[i];
}

// ================= sliced fill (scalar, grid-stride) =================
__global__ __launch_bounds__(256) void fill_sliced_kernel(
    const int* __restrict__ nidx, const int* __restrict__ eidx,
    const int* __restrict__ e_off, const int* __restrict__ n_off,
    int* __restrict__ ecur, int* __restrict__ ncur,
    int* __restrict__ e_nodes, int* __restrict__ n_edges, int nnz, int n) {
  int slice = blockIdx.x & (NSLICE - 1);
  int bid = blockIdx.x >> 3;
  int bps = gridDim.x >> 3;
  int elo = EDGES * slice / NSLICE, ehi = EDGES * (slice + 1) / NSLICE;
  int nlo = (int)((long long)n * slice / NSLICE);
  int nhi = (int)((long long)n * (slice + 1) / NSLICE);
  for (int p = bid * 256 + threadIdx.x; p < nnz; p += bps * 256) {
    int v = nidx[p], e = eidx[p];
    if (e >= elo && e < ehi) {
      int pe = e_off[e] + atomicAdd(&ecur[e], 1);
      e_nodes[pe] = v;
    }
    if (v >= nlo && v < nhi) {
      int pn = n_off[v] + atomicAdd(&ncur[v], 1);
      n_edges[pn] = e;
    }
  }
}

// ================= segment-mean gather: one wave per segment =================
template <typename SrcT, typename DstT>
__global__ __launch_bounds__(256) void gather_mean_kernel(
    const SrcT* __restrict__ src, const int* __restrict__ off,
    const int* __restrict__ list, DstT* __restrict__ dst, int nseg) {
  int seg = blockIdx.x * 4 + (threadIdx.x >> 6);
  if (seg >= nseg) return;
  int lane = threadIdx.x & 63;
  int col = lane * 2;
  int s0 = off[seg], s1 = off[seg + 1];
  float ax = 0.f, ay = 0.f;
  for (int base = s0; base < s1; base += 64) {
    int m = base + lane;
    int myidx = (m < s1) ? list[m] : 0;
    int cnt = min(64, s1 - base);
    int j = 0;
    for (; j + 4 <= cnt; j += 4) {
      int r0 = __shfl(myidx, j + 0);
      int r1 = __shfl(myidx, j + 1);
      int r2 = __shfl(myidx, j + 2);
      int r3 = __shfl(myidx, j + 3);
      float2 v0 = load2(&src[(size_t)r0 * D + col]);
      float2 v1 = load2(&src[(size_t)r1 * D + col]);
      float2 v2 = load2(&src[(size_t)r2 * D + col]);
      float2 v3 = load2(&src[(size_t)r3 * D + col]);
      ax += v0.x + v1.x + v2.x + v3.x;
      ay += v0.y + v1.y + v2.y + v3.y;
    }
    for (; j < cnt; ++j) {
      int r = __shfl(myidx, j);
      float2 v = load2(&src[(size_t)r * D + col]);
      ax += v.x; ay += v.y;
    }
  }
  float inv = 1.0f / fmaxf((float)(s1 - s0), 1.0f);
  float2 o; o.x = ax * inv; o.y = ay * inv;
  store2(&dst[(size_t)seg * D + col], o);
}

// ====== register-tiled GEMM + fused attention (no LDS), bf16 in/out ======
__device__ inline float4 f4fma(float s, float4 b, float4 acc) {
  acc.x = fmaf(s, b.x, acc.x); acc.y = fmaf(s, b.y, acc.y);
  acc.z = fmaf(s, b.z, acc.z); acc.w = fmaf(s, b.w, acc.w);
  return acc;
}

__global__ __launch_bounds__(256) void gemm_att_kernel(
    const unsigned short* __restrict__ xm3, const float* __restrict__ theta,
    const float* __restrict__ bias, const float* __restrict__ att_w,
    const float* __restrict__ att_b, unsigned short* __restrict__ ef2,
    float* __restrict__ w, int e_count) {
  int tid = threadIdx.x;
  int cg = tid & 31;            // col group: cols cg*4 .. +3
  int rg = tid >> 5;            // row group: rows row0 .. +3
  int row0 = blockIdx.x * 32 + rg * 4;
  int c0 = cg * 4;

  const unsigned short* ap[4];
#pragma unroll
  for (int r = 0; r < 4; ++r) {
    int rr = min(row0 + r, e_count - 1);
    ap[r] = xm3 + (size_t)rr * D;
  }

  float4 acc[4];
#pragma unroll
  for (int r = 0; r < 4; ++r) acc[r] = make_float4(0.f, 0.f, 0.f, 0.f);

#pragma unroll 2
  for (int k = 0; k < D; k += 4) {
    float4 b0 = *(const float4*)&theta[(k + 0) * D + c0];
    float4 b1 = *(const float4*)&theta[(k + 1) * D + c0];
    float4 b2 = *(const float4*)&theta[(k + 2) * D + c0];
    float4 b3 = *(const float4*)&theta[(k + 3) * D + c0];
#pragma unroll
    for (int r = 0; r < 4; ++r) {
      ushort4 a4 = *(const ushort4*)(ap[r] + k);
      acc[r] = f4fma(bf2f(a4.x), b0, acc[r]);
      acc[r] = f4fma(bf2f(a4.y), b1, acc[r]);
      acc[r] = f4fma(bf2f(a4.z), b2, acc[r]);
      acc[r] = f4fma(bf2f(a4.w), b3, acc[r]);
    }
  }

  float4 bv = *(const float4*)&bias[c0];
  float4 awv = *(const float4*)&att_w[c0];
  float ab = att_b[0];
  float part[4];
#pragma unroll
  for (int r = 0; r < 4; ++r) {
    acc[r].x += bv.x; acc[r].y += bv.y; acc[r].z += bv.z; acc[r].w += bv.w;
    part[r] = acc[r].x * awv.x + acc[r].y * awv.y +
              acc[r].z * awv.z + acc[r].w * awv.w;
  }
  // reduce attention partials across the 32 col-group lanes
#pragma unroll
  for (int off = 16; off >= 1; off >>= 1) {
#pragma unroll
    for (int r = 0; r < 4; ++r) part[r] += __shfl_xor(part[r], off);
  }
#pragma unroll
  for (int r = 0; r < 4; ++r) {
    if (row0 + r < e_count) {
      ushort4 o;
      o.x = f2bf(acc[r].x); o.y = f2bf(acc[r].y);
      o.z = f2bf(acc[r].z); o.w = f2bf(acc[r].w);
      *(ushort4*)&ef2[(size_t)(row0 + r) * D + c0] = o;
    }
  }
  if (cg == 0) {
    float s[4];
#pragma unroll
    for (int r = 0; r < 4; ++r) s[r] = 1.0f / (1.0f + expf(-(part[r] + ab)));
    if (row0 + 3 < e_count) {
      *(float4*)&w[row0] = make_float4(s[0], s[1], s[2], s[3]);
    } else {
#pragma unroll
      for (int r = 0; r < 4; ++r)
        if (row0 + r < e_count) w[row0 + r] = s[r];
    }
  }
}

// ====== final: out[v] = sum_e w[e]*ef2[e] / max(sum_e w[e], 1e-12) ======
__global__ __launch_bounds__(256) void gather_weighted_kernel(
    const unsigned short* __restrict__ ef, const float* __restrict__ w,
    const int* __restrict__ off, const int* __restrict__ list,
    float* __restrict__ out, int nseg) {
  int seg = blockIdx.x * 4 + (threadIdx.x >> 6);
  if (seg >= nseg) return;
  int lane = threadIdx.x & 63;
  int col = lane * 2;
  int s0 = off[seg], s1 = off[seg + 1];
  float ax = 0.f, ay = 0.f, wsum = 0.f;
  for (int base = s0; base < s1; base += 64) {
    int m = base + lane;
    int myidx = (m < s1) ? list[m] : 0;
    float myw = (m < s1) ? w[myidx] : 0.f;
    int cnt = min(64, s1 - base);
    int j = 0;
    for (; j + 2 <= cnt; j += 2) {
      int r0 = __shfl(myidx, j + 0);
      int r1 = __shfl(myidx, j + 1);
      float w0 = __shfl(myw, j + 0);
      float w1 = __shfl(myw, j + 1);
      float2 v0 = load2(&ef[(size_t)r0 * D + col]);
      float2 v1 = load2(&ef[(size_t)r1 * D + col]);
      ax = fmaf(w0, v0.x, ax); ay = fmaf(w0, v0.y, ay);
      ax = fmaf(w1, v1.x, ax); ay = fmaf(w1, v1.y, ay);
      wsum += w0 + w1;
    }
    for (; j < cnt; ++j) {
      int r = __shfl(myidx, j);
      float w0 = __shfl(myw, j);
      float2 v = load2(&ef[(size_t)r * D + col]);
      ax = fmaf(w0, v.x, ax); ay = fmaf(w0, v.y, ay);
      wsum += w0;
    }
  }
  float invd = 1.0f / fmaxf(wsum, 1e-12f);
  float2 o; o.x = ax * invd; o.y = ay * invd;
  *(float2*)&out[(size_t)seg * D + col] = o;
}

extern "C" void kernel_launch(void* const* d_in, const int* in_sizes, int n_in,
                              void* d_out, int out_size, void* d_ws, size_t ws_size,
                              hipStream_t stream) {
  const float* x        = (const float*)d_in[0];
  const float* theta    = (const float*)d_in[1];
  const float* bias     = (const float*)d_in[2];
  const float* att_w    = (const float*)d_in[3];
  const float* att_b    = (const float*)d_in[4];
  const int*   node_idx = (const int*)d_in[5];
  const int*   edge_idx = (const int*)d_in[6];
  int n   = in_sizes[0] / D;   // 100000
  int nnz = in_sizes[5];       // 800000
  int E   = EDGES;             // 25000
  float* out = (float*)d_out;

  // ---- workspace layout ----
  char* p = (char*)d_ws;
  unsigned short* xm1 = (unsigned short*)p;  p += (size_t)E * D * sizeof(unsigned short);
  unsigned short* xm2 = (unsigned short*)p;  p += (size_t)n * D * sizeof(unsigned short);
  unsigned short* xm3 = (unsigned short*)p;  p += (size_t)E * D * sizeof(unsigned short);
  unsigned short* ef2 = (unsigned short*)p;  p += (size_t)E * D * sizeof(unsigned short);
  float* w     = (float*)p;         p += (size_t)E * sizeof(float);
  int* e_off   = (int*)p;           p += (size_t)(E + 1) * sizeof(int);
  int* n_off   = (int*)p;           p += (size_t)(n + 1) * sizeof(int);
  int* e_nodes = (int*)p;           p += (size_t)nnz * sizeof(int);
  int* n_edges = (int*)p;           p += (size_t)nnz * sizeof(int);
  int* ecnt    = (int*)p;           p += (size_t)E * sizeof(int);   // also cursor
  int* ncnt    = (int*)p;           p += (size_t)n * sizeof(int);   // also cursor
  int* bsum    = (int*)p;           p += 1024 * sizeof(int);
  int* dummy   = (int*)p;           p += 64 * sizeof(int);

  int nb_e = (E + 1023) / 1024;    // 25
  int nb_n = (n + 1023) / 1024;    // 98
  int sliced_grid = 256 * NSLICE;  // 2048 blocks, 256 per slice

  // ---- CSR build ----
  hipMemsetAsync(ecnt, 0, ((size_t)E + n) * sizeof(int), stream);
  hist_sliced_kernel<<<sliced_grid, 256, 0, stream>>>(node_idx, edge_idx, ncnt, ecnt, nnz, n);

  scan_block_kernel<<<nb_e, 256, 0, stream>>>(ecnt, e_off, bsum, E);
  scan_block_kernel<<<1, 256, 0, stream>>>(bsum, bsum, dummy, nb_e);
  scan_add_kernel<<<(E + 255) / 256, 256, 0, stream>>>(e_off, bsum, ecnt, E);

  scan_block_kernel<<<nb_n, 256, 0, stream>>>(ncnt, n_off, bsum, n);
  scan_block_kernel<<<1, 256, 0, stream>>>(bsum, bsum, dummy, nb_n);
  scan_add_kernel<<<(n + 255) / 256, 256, 0, stream>>>(n_off, bsum, ncnt, n);

  hipMemsetAsync(ecnt, 0, ((size_t)E + n) * sizeof(int), stream);  // cursors
  fill_sliced_kernel<<<sliced_grid, 256, 0, stream>>>(
      node_idx, edge_idx, e_off, n_off, ecnt, ncnt, e_nodes, n_edges, nnz, n);

  // ---- 1) xm1[e] = mean over edge members of x (fp32 -> bf16) ----
  gather_mean_kernel<float, unsigned short>
      <<<(E + 3) / 4, 256, 0, stream>>>(x, e_off, e_nodes, xm1, E);

  // ---- 2) xm2[v] = mean over node's incident edges of xm1 (bf16 -> bf16) ----
  gather_mean_kernel<unsigned short, unsigned short>
      <<<(n + 3) / 4, 256, 0, stream>>>(xm1, n_off, n_edges, xm2, n);

  // ---- 3) xm3[e] = mean over edge members of xm2 (bf16 -> bf16) ----
  gather_mean_kernel<unsigned short, unsigned short>
      <<<(E + 3) / 4, 256, 0, stream>>>(xm2, e_off, e_nodes, xm3, E);

  // ---- 4) ef2 = xm3@theta + bias; w = sigmoid(ef2 @ att_w + att_b) ----
  gemm_att_kernel<<<(E + 31) / 32, 256, 0, stream>>>(
      xm3, theta, bias, att_w, att_b, ef2, w, E);

  // ---- 5) out[v] = weighted mean of ef2 over v's incident edges ----
  gather_weighted_kernel<<<(n + 3) / 4, 256, 0, stream>>>(ef2, w, n_off, n_edges, out, n);
}

// Round 8
// 339.522 us; speedup vs baseline: 16.8229x; 1.0992x over previous
//
#include <hip/hip_runtime.h>

#define D 128
#define EDGES 25000
#define NSLICE 8

// ---------------- bf16 helpers (round-to-nearest-even) ----------------
__device__ inline float bf2f(unsigned short h) {
  return __uint_as_float(((unsigned)h) << 16);
}
__device__ inline unsigned short f2bf(float f) {
  unsigned u = __float_as_uint(f);
  u += 0x7FFFu + ((u >> 16) & 1u);
  return (unsigned short)(u >> 16);
}
__device__ inline float2 load2(const float* p) { return *(const float2*)p; }
__device__ inline float2 load2(const unsigned short* p) {
  ushort2 u = *(const ushort2*)p;
  float2 v; v.x = bf2f(u.x); v.y = bf2f(u.y);
  return v;
}
__device__ inline void store2(float* p, float2 v) { *(float2*)p = v; }
__device__ inline void store2(unsigned short* p, float2 v) {
  ushort2 u; u.x = f2bf(v.x); u.y = f2bf(v.y);
  *(ushort2*)p = u;
}

// ================= dense fp32 -> bf16 conversion =================
__global__ __launch_bounds__(256) void cvt_bf16_kernel(
    const float* __restrict__ in, unsigned short* __restrict__ out, int n4) {
  // n4 = number of float4 groups
  for (int i = blockIdx.x * 256 + threadIdx.x; i < n4; i += gridDim.x * 256) {
    float4 v = *(const float4*)&in[(size_t)i * 4];
    ushort4 o;
    o.x = f2bf(v.x); o.y = f2bf(v.y); o.z = f2bf(v.z); o.w = f2bf(v.w);
    *(ushort4*)&out[(size_t)i * 4] = o;
  }
}

// ================= sliced histogram (scalar, grid-stride) =================
__global__ __launch_bounds__(256) void hist_sliced_kernel(
    const int* __restrict__ nidx, const int* __restrict__ eidx,
    int* __restrict__ ncnt, int* __restrict__ ecnt, int nnz, int n) {
  int slice = blockIdx.x & (NSLICE - 1);
  int bid = blockIdx.x >> 3;                 // block index within slice
  int bps = gridDim.x >> 3;                  // blocks per slice
  int elo = EDGES * slice / NSLICE, ehi = EDGES * (slice + 1) / NSLICE;
  int nlo = (int)((long long)n * slice / NSLICE);
  int nhi = (int)((long long)n * (slice + 1) / NSLICE);
  for (int p = bid * 256 + threadIdx.x; p < nnz; p += bps * 256) {
    int e = eidx[p], v = nidx[p];
    if (e >= elo && e < ehi) atomicAdd(&ecnt[e], 1);
    if (v >= nlo && v < nhi) atomicAdd(&ncnt[v], 1);
  }
}

// exclusive scan, 1024 elems per block (4/thread), Hillis-Steele in LDS
__global__ __launch_bounds__(256) void scan_block_kernel(
    const int* __restrict__ in, int* __restrict__ out, int* __restrict__ bsum, int n) {
  __shared__ int s[256];
  int t = threadIdx.x;
  int base = blockIdx.x * 1024 + t * 4;
  int c0 = (base + 0 < n) ? in[base + 0] : 0;
  int c1 = (base + 1 < n) ? in[base + 1] : 0;
  int c2 = (base + 2 < n) ? in[base + 2] : 0;
  int c3 = (base + 3 < n) ? in[base + 3] : 0;
  int lsum = c0 + c1 + c2 + c3;
  s[t] = lsum;
  __syncthreads();
  for (int off = 1; off < 256; off <<= 1) {
    int a = (t >= off) ? s[t - off] : 0;
    __syncthreads();
    s[t] += a;
    __syncthreads();
  }
  int excl = s[t] - lsum;
  if (base + 0 < n) out[base + 0] = excl;
  if (base + 1 < n) out[base + 1] = excl + c0;
  if (base + 2 < n) out[base + 2] = excl + c0 + c1;
  if (base + 3 < n) out[base + 3] = excl + c0 + c1 + c2;
  if (t == 255) bsum[blockIdx.x] = s[255];
}

__global__ __launch_bounds__(256) void scan_add_kernel(
    int* __restrict__ out, const int* __restrict__ bsum,
    const int* __restrict__ cnt, int n) {
  int i = blockIdx.x * 256 + threadIdx.x;
  if (i >= n) return;
  int v = out[i] + bsum[i >> 10];
  out[i] = v;
  if (i == n - 1) out[n] = v + cnt[i];
}

// ================= sliced fill (scalar, grid-stride) =================
// n_edges is ushort (edge ids < 25000).
__global__ __launch_bounds__(256) void fill_sliced_kernel(
    const int* __restrict__ nidx, const int* __restrict__ eidx,
    const int* __restrict__ e_off, const int* __restrict__ n_off,
    int* __restrict__ ecur, int* __restrict__ ncur,
    int* __restrict__ e_nodes, unsigned short* __restrict__ n_edges,
    int nnz, int n) {
  int slice = blockIdx.x & (NSLICE - 1);
  int bid = blockIdx.x >> 3;
  int bps = gridDim.x >> 3;
  int elo = EDGES * slice / NSLICE, ehi = EDGES * (slice + 1) / NSLICE;
  int nlo = (int)((long long)n * slice / NSLICE);
  int nhi = (int)((long long)n * (slice + 1) / NSLICE);
  for (int p = bid * 256 + threadIdx.x; p < nnz; p += bps * 256) {
    int v = nidx[p], e = eidx[p];
    if (e >= elo && e < ehi) {
      int pe = e_off[e] + atomicAdd(&ecur[e], 1);
      e_nodes[pe] = v;
    }
    if (v >= nlo && v < nhi) {
      int pn = n_off[v] + atomicAdd(&ncur[v], 1);
      n_edges[pn] = (unsigned short)e;
    }
  }
}

// ================= segment-mean gather: one wave per segment =================
template <typename SrcT, typename DstT, typename IdxT>
__global__ __launch_bounds__(256) void gather_mean_kernel(
    const SrcT* __restrict__ src, const int* __restrict__ off,
    const IdxT* __restrict__ list, DstT* __restrict__ dst, int nseg) {
  int seg = blockIdx.x * 4 + (threadIdx.x >> 6);
  if (seg >= nseg) return;
  int lane = threadIdx.x & 63;
  int col = lane * 2;
  int s0 = off[seg], s1 = off[seg + 1];
  float ax = 0.f, ay = 0.f;
  for (int base = s0; base < s1; base += 64) {
    int m = base + lane;
    int myidx = (m < s1) ? (int)list[m] : 0;
    int cnt = min(64, s1 - base);
    int j = 0;
    for (; j + 8 <= cnt; j += 8) {
      int r0 = __shfl(myidx, j + 0);
      int r1 = __shfl(myidx, j + 1);
      int r2 = __shfl(myidx, j + 2);
      int r3 = __shfl(myidx, j + 3);
      int r4 = __shfl(myidx, j + 4);
      int r5 = __shfl(myidx, j + 5);
      int r6 = __shfl(myidx, j + 6);
      int r7 = __shfl(myidx, j + 7);
      float2 v0 = load2(&src[(size_t)r0 * D + col]);
      float2 v1 = load2(&src[(size_t)r1 * D + col]);
      float2 v2 = load2(&src[(size_t)r2 * D + col]);
      float2 v3 = load2(&src[(size_t)r3 * D + col]);
      float2 v4 = load2(&src[(size_t)r4 * D + col]);
      float2 v5 = load2(&src[(size_t)r5 * D + col]);
      float2 v6 = load2(&src[(size_t)r6 * D + col]);
      float2 v7 = load2(&src[(size_t)r7 * D + col]);
      ax += (v0.x + v1.x) + (v2.x + v3.x) + (v4.x + v5.x) + (v6.x + v7.x);
      ay += (v0.y + v1.y) + (v2.y + v3.y) + (v4.y + v5.y) + (v6.y + v7.y);
    }
    for (; j + 4 <= cnt; j += 4) {
      int r0 = __shfl(myidx, j + 0);
      int r1 = __shfl(myidx, j + 1);
      int r2 = __shfl(myidx, j + 2);
      int r3 = __shfl(myidx, j + 3);
      float2 v0 = load2(&src[(size_t)r0 * D + col]);
      float2 v1 = load2(&src[(size_t)r1 * D + col]);
      float2 v2 = load2(&src[(size_t)r2 * D + col]);
      float2 v3 = load2(&src[(size_t)r3 * D + col]);
      ax += (v0.x + v1.x) + (v2.x + v3.x);
      ay += (v0.y + v1.y) + (v2.y + v3.y);
    }
    for (; j < cnt; ++j) {
      int r = __shfl(myidx, j);
      float2 v = load2(&src[(size_t)r * D + col]);
      ax += v.x; ay += v.y;
    }
  }
  float inv = 1.0f / fmaxf((float)(s1 - s0), 1.0f);
  float2 o; o.x = ax * inv; o.y = ay * inv;
  store2(&dst[(size_t)seg * D + col], o);
}

// ====== register-tiled GEMM + fused attention (no LDS), bf16 in/out ======
__device__ inline float4 f4fma(float s, float4 b, float4 acc) {
  acc.x = fmaf(s, b.x, acc.x); acc.y = fmaf(s, b.y, acc.y);
  acc.z = fmaf(s, b.z, acc.z); acc.w = fmaf(s, b.w, acc.w);
  return acc;
}

__global__ __launch_bounds__(256) void gemm_att_kernel(
    const unsigned short* __restrict__ xm3, const float* __restrict__ theta,
    const float* __restrict__ bias, const float* __restrict__ att_w,
    const float* __restrict__ att_b, unsigned short* __restrict__ ef2,
    float* __restrict__ w, int e_count) {
  int tid = threadIdx.x;
  int cg = tid & 31;            // col group: cols cg*4 .. +3
  int rg = tid >> 5;            // row group: rows row0 .. +3
  int row0 = blockIdx.x * 32 + rg * 4;
  int c0 = cg * 4;

  const unsigned short* ap[4];
#pragma unroll
  for (int r = 0; r < 4; ++r) {
    int rr = min(row0 + r, e_count - 1);
    ap[r] = xm3 + (size_t)rr * D;
  }

  float4 acc[4];
#pragma unroll
  for (int r = 0; r < 4; ++r) acc[r] = make_float4(0.f, 0.f, 0.f, 0.f);

#pragma unroll 2
  for (int k = 0; k < D; k += 4) {
    float4 b0 = *(const float4*)&theta[(k + 0) * D + c0];
    float4 b1 = *(const float4*)&theta[(k + 1) * D + c0];
    float4 b2 = *(const float4*)&theta[(k + 2) * D + c0];
    float4 b3 = *(const float4*)&theta[(k + 3) * D + c0];
#pragma unroll
    for (int r = 0; r < 4; ++r) {
      ushort4 a4 = *(const ushort4*)(ap[r] + k);
      acc[r] = f4fma(bf2f(a4.x), b0, acc[r]);
      acc[r] = f4fma(bf2f(a4.y), b1, acc[r]);
      acc[r] = f4fma(bf2f(a4.z), b2, acc[r]);
      acc[r] = f4fma(bf2f(a4.w), b3, acc[r]);
    }
  }

  float4 bv = *(const float4*)&bias[c0];
  float4 awv = *(const float4*)&att_w[c0];
  float ab = att_b[0];
  float part[4];
#pragma unroll
  for (int r = 0; r < 4; ++r) {
    acc[r].x += bv.x; acc[r].y += bv.y; acc[r].z += bv.z; acc[r].w += bv.w;
    part[r] = acc[r].x * awv.x + acc[r].y * awv.y +
              acc[r].z * awv.z + acc[r].w * awv.w;
  }
  // reduce attention partials across the 32 col-group lanes
#pragma unroll
  for (int off = 16; off >= 1; off >>= 1) {
#pragma unroll
    for (int r = 0; r < 4; ++r) part[r] += __shfl_xor(part[r], off);
  }
#pragma unroll
  for (int r = 0; r < 4; ++r) {
    if (row0 + r < e_count) {
      ushort4 o;
      o.x = f2bf(acc[r].x); o.y = f2bf(acc[r].y);
      o.z = f2bf(acc[r].z); o.w = f2bf(acc[r].w);
      *(ushort4*)&ef2[(size_t)(row0 + r) * D + c0] = o;
    }
  }
  if (cg == 0) {
    float s[4];
#pragma unroll
    for (int r = 0; r < 4; ++r) s[r] = 1.0f / (1.0f + expf(-(part[r] + ab)));
    if (row0 + 3 < e_count) {
      *(float4*)&w[row0] = make_float4(s[0], s[1], s[2], s[3]);
    } else {
#pragma unroll
      for (int r = 0; r < 4; ++r)
        if (row0 + r < e_count) w[row0 + r] = s[r];
    }
  }
}

// ====== final: out[v] = sum_e w[e]*ef2[e] / max(sum_e w[e], 1e-12) ======
__global__ __launch_bounds__(256) void gather_weighted_kernel(
    const unsigned short* __restrict__ ef, const float* __restrict__ w,
    const int* __restrict__ off, const unsigned short* __restrict__ list,
    float* __restrict__ out, int nseg) {
  int seg = blockIdx.x * 4 + (threadIdx.x >> 6);
  if (seg >= nseg) return;
  int lane = threadIdx.x & 63;
  int col = lane * 2;
  int s0 = off[seg], s1 = off[seg + 1];
  float ax = 0.f, ay = 0.f, wsum = 0.f;
  for (int base = s0; base < s1; base += 64) {
    int m = base + lane;
    int myidx = (m < s1) ? (int)list[m] : 0;
    float myw = (m < s1) ? w[myidx] : 0.f;
    int cnt = min(64, s1 - base);
    int j = 0;
    for (; j + 4 <= cnt; j += 4) {
      int r0 = __shfl(myidx, j + 0);
      int r1 = __shfl(myidx, j + 1);
      int r2 = __shfl(myidx, j + 2);
      int r3 = __shfl(myidx, j + 3);
      float w0 = __shfl(myw, j + 0);
      float w1 = __shfl(myw, j + 1);
      float w2 = __shfl(myw, j + 2);
      float w3 = __shfl(myw, j + 3);
      float2 v0 = load2(&ef[(size_t)r0 * D + col]);
      float2 v1 = load2(&ef[(size_t)r1 * D + col]);
      float2 v2 = load2(&ef[(size_t)r2 * D + col]);
      float2 v3 = load2(&ef[(size_t)r3 * D + col]);
      ax = fmaf(w0, v0.x, ax); ay = fmaf(w0, v0.y, ay);
      ax = fmaf(w1, v1.x, ax); ay = fmaf(w1, v1.y, ay);
      ax = fmaf(w2, v2.x, ax); ay = fmaf(w2, v2.y, ay);
      ax = fmaf(w3, v3.x, ax); ay = fmaf(w3, v3.y, ay);
      wsum += (w0 + w1) + (w2 + w3);
    }
    for (; j < cnt; ++j) {
      int r = __shfl(myidx, j);
      float w0 = __shfl(myw, j);
      float2 v = load2(&ef[(size_t)r * D + col]);
      ax = fmaf(w0, v.x, ax); ay = fmaf(w0, v.y, ay);
      wsum += w0;
    }
  }
  float invd = 1.0f / fmaxf(wsum, 1e-12f);
  float2 o; o.x = ax * invd; o.y = ay * invd;
  *(float2*)&out[(size_t)seg * D + col] = o;
}

extern "C" void kernel_launch(void* const* d_in, const int* in_sizes, int n_in,
                              void* d_out, int out_size, void* d_ws, size_t ws_size,
                              hipStream_t stream) {
  const float* x        = (const float*)d_in[0];
  const float* theta    = (const float*)d_in[1];
  const float* bias     = (const float*)d_in[2];
  const float* att_w    = (const float*)d_in[3];
  const float* att_b    = (const float*)d_in[4];
  const int*   node_idx = (const int*)d_in[5];
  const int*   edge_idx = (const int*)d_in[6];
  int n   = in_sizes[0] / D;   // 100000
  int nnz = in_sizes[5];       // 800000
  int E   = EDGES;             // 25000
  float* out = (float*)d_out;

  // ---- workspace layout ----
  char* p = (char*)d_ws;
  unsigned short* xb  = (unsigned short*)p;  p += (size_t)n * D * sizeof(unsigned short);
  unsigned short* xm1 = (unsigned short*)p;  p += (size_t)E * D * sizeof(unsigned short);
  unsigned short* xm2 = (unsigned short*)p;  p += (size_t)n * D * sizeof(unsigned short);
  unsigned short* xm3 = (unsigned short*)p;  p += (size_t)E * D * sizeof(unsigned short);
  unsigned short* ef2 = (unsigned short*)p;  p += (size_t)E * D * sizeof(unsigned short);
  float* w     = (float*)p;         p += (size_t)E * sizeof(float);
  int* e_off   = (int*)p;           p += (size_t)(E + 1) * sizeof(int);
  int* n_off   = (int*)p;           p += (size_t)(n + 1) * sizeof(int);
  int* e_nodes = (int*)p;           p += (size_t)nnz * sizeof(int);
  unsigned short* n_edges = (unsigned short*)p;
  p += (((size_t)nnz * sizeof(unsigned short) + 3) & ~(size_t)3);
  int* ecnt    = (int*)p;           p += (size_t)E * sizeof(int);   // also cursor
  int* ncnt    = (int*)p;           p += (size_t)n * sizeof(int);   // also cursor
  int* bsum    = (int*)p;           p += 1024 * sizeof(int);
  int* dummy   = (int*)p;           p += 64 * sizeof(int);

  int nb_e = (E + 1023) / 1024;    // 25
  int nb_n = (n + 1023) / 1024;    // 98
  int sliced_grid = 256 * NSLICE;  // 2048 blocks, 256 per slice

  // ---- x -> bf16 dense conversion ----
  cvt_bf16_kernel<<<2048, 256, 0, stream>>>(x, xb, n * D / 4);

  // ---- CSR build ----
  hipMemsetAsync(ecnt, 0, ((size_t)E + n) * sizeof(int), stream);
  hist_sliced_kernel<<<sliced_grid, 256, 0, stream>>>(node_idx, edge_idx, ncnt, ecnt, nnz, n);

  scan_block_kernel<<<nb_e, 256, 0, stream>>>(ecnt, e_off, bsum, E);
  scan_block_kernel<<<1, 256, 0, stream>>>(bsum, bsum, dummy, nb_e);
  scan_add_kernel<<<(E + 255) / 256, 256, 0, stream>>>(e_off, bsum, ecnt, E);

  scan_block_kernel<<<nb_n, 256, 0, stream>>>(ncnt, n_off, bsum, n);
  scan_block_kernel<<<1, 256, 0, stream>>>(bsum, bsum, dummy, nb_n);
  scan_add_kernel<<<(n + 255) / 256, 256, 0, stream>>>(n_off, bsum, ncnt, n);

  hipMemsetAsync(ecnt, 0, ((size_t)E + n) * sizeof(int), stream);  // cursors
  fill_sliced_kernel<<<sliced_grid, 256, 0, stream>>>(
      node_idx, edge_idx, e_off, n_off, ecnt, ncnt, e_nodes, n_edges, nnz, n);

  // ---- 1) xm1[e] = mean over edge members of xb (bf16 -> bf16) ----
  gather_mean_kernel<unsigned short, unsigned short, int>
      <<<(E + 3) / 4, 256, 0, stream>>>(xb, e_off, e_nodes, xm1, E);

  // ---- 2) xm2[v] = mean over node's incident edges of xm1 (bf16 -> bf16) ----
  gather_mean_kernel<unsigned short, unsigned short, unsigned short>
      <<<(n + 3) / 4, 256, 0, stream>>>(xm1, n_off, n_edges, xm2, n);

  // ---- 3) xm3[e] = mean over edge members of xm2 (bf16 -> bf16) ----
  gather_mean_kernel<unsigned short, unsigned short, int>
      <<<(E + 3) / 4, 256, 0, stream>>>(xm2, e_off, e_nodes, xm3, E);

  // ---- 4) ef2 = xm3@theta + bias; w = sigmoid(ef2 @ att_w + att_b) ----
  gemm_att_kernel<<<(E + 31) / 32, 256, 0, stream>>>(
      xm3, theta, bias, att_w, att_b, ef2, w, E);

  // ---- 5) out[v] = weighted mean of ef2 over v's incident edges ----
  gather_weighted_kernel<<<(n + 3) / 4, 256, 0, stream>>>(ef2, w, n_off, n_edges, out, n);
}